// Round 7
// baseline (217.878 us; speedup 1.0000x reference)
//
#include <hip/hip_runtime.h>
#include <hip/hip_bf16.h>

// GraphAutoencoder: 3x GraphConv (DGL norm='both') on fixed graph.
// N=50000 nodes, E=600000 edges, widths 128 -> 64 -> 32 -> 128.
//
// R1: scatter-atomics RMW-bound (485us). R2: CSR+gather -> 340us.
// R3: tiled GEMM/gathers -> 277us. R4: atomic-free counting sort -> 243us.
//     (harness 0xAA poison of 256MiB ws = fixed ~44us inside timed window)
// R5: bf16 gather sources + zb shadow -> 223us. R6: row-local fusion
//     (gather+GEMM in B and D) -> 213us.
// R7: degree-sorted node permutation for the gather kernels. Wave-groups
//     process nodes in lockstep to the group's MAX degree; Poisson(12)
//     degrees waste ~30% of loop trips (E[max of 8]~16 vs mean 12).
//     Sorting nodes by in-degree makes loop lengths uniform. Perm only
//     remaps node->wave; per-node CSR sum order unchanged -> bit-identical.
//     Also: scan2 folded into scan3 (redundant per-block scan of blocksums).
//
// Pipeline:
//   A: t1b = bf16(rs_out .* (X @ W1))                      [GEMM]
//   B: node=perm[g]: agg=gather(t1b); h=relu(rs_in*agg+b1);
//      t2b = bf16(rs_out .* (h @ W2))                      [fused]
//   C: node=perm[g]: z = rs_in*gather(t2b)+b2 -> d_out; zb = bf16(z*rs_out)
//   D: node=perm[g]: recon = (rs_in .* gather(zb)) @ W3 + b3 -> d_out

#define HNB 4          // node bins
#define HPB 64         // edge partitions
#define HBIN 12500     // nodes per bin (HNB*HBIN == N)
#define DB 64          // degree-sort bins (clipped)
typedef unsigned short u16;

__device__ __forceinline__ float bfhi(unsigned u) {
    unsigned v = u & 0xFFFF0000u;
    return __builtin_bit_cast(float, v);
}
__device__ __forceinline__ float bflo(unsigned u) {
    unsigned v = u << 16;
    return __builtin_bit_cast(float, v);
}
__device__ __forceinline__ unsigned f2bf(float f) {   // f32 -> bf16 RNE
    unsigned u = __builtin_bit_cast(unsigned, f);
    return (u + 0x7FFFu + ((u >> 16) & 1u)) >> 16;
}

// ---------------- histogram: u16 slab[2][HNB][HPB][HBIN] ----------------
__global__ __launch_bounds__(256) void k_hist2(
    const int* __restrict__ src, const int* __restrict__ dst,
    u16* __restrict__ slab, int* __restrict__ degcnt, int E, int slice)
{
    __shared__ int h[HBIN];
    if (blockIdx.x == 0 && threadIdx.x < DB) degcnt[threadIdx.x] = 0;  // zero for reduce
    const int which = blockIdx.x / (HNB * HPB);
    const int bin   = (blockIdx.x / HPB) % HNB;
    const int p     = blockIdx.x % HPB;
    const int* __restrict__ idx = which ? dst : src;

    for (int i = threadIdx.x; i < HBIN; i += 256) h[i] = 0;
    __syncthreads();

    const int lo  = bin * HBIN;
    const int beg = p * slice;
    const int fin = min(beg + slice, E);
    for (int i = beg + threadIdx.x * 4; i + 3 < fin; i += 1024) {
        const int4 v = *(const int4*)(idx + i);
        int u;
        u = v.x - lo; if ((unsigned)u < (unsigned)HBIN) atomicAdd(&h[u], 1);
        u = v.y - lo; if ((unsigned)u < (unsigned)HBIN) atomicAdd(&h[u], 1);
        u = v.z - lo; if ((unsigned)u < (unsigned)HBIN) atomicAdd(&h[u], 1);
        u = v.w - lo; if ((unsigned)u < (unsigned)HBIN) atomicAdd(&h[u], 1);
    }
    for (int i = beg + ((fin - beg) & ~3) + threadIdx.x; i < fin; i += 256) {
        int u = idx[i] - lo;
        if ((unsigned)u < (unsigned)HBIN) atomicAdd(&h[u], 1);
    }
    __syncthreads();

    unsigned* out = (unsigned*)(slab + (size_t)blockIdx.x * HBIN);
    for (int i = threadIdx.x; i < HBIN / 2; i += 256)
        out[i] = (unsigned)h[2 * i] | ((unsigned)h[2 * i + 1] << 16);
}

// degrees -> rsqrt + deg[]; dst half -> per-partition excl offsets (in place);
// block-level inclusive scan of in-degree; LDS degree-histogram -> degcnt.
__global__ __launch_bounds__(256) void k_reduce_scan(
    u16* __restrict__ slab, float* __restrict__ rs_out, float* __restrict__ rs_in,
    int* __restrict__ partial, int* __restrict__ blocksum,
    int* __restrict__ deg, int* __restrict__ degcnt, int N)
{
    __shared__ int tmp[256];
    __shared__ int dh[DB];
    const int tid = threadIdx.x;
    const int i = blockIdx.x * 256 + tid;
    if (tid < DB) dh[tid] = 0;

    int run = 0;
    if (i < N) {
        const int bin = i / HBIN;
        const int off = i - bin * HBIN;
        const u16* s_src = slab + ((size_t)(bin * HPB)) * HBIN + off;
        u16*       s_dst = slab + ((size_t)((HNB + bin) * HPB)) * HBIN + off;

        int so = 0;
#pragma unroll
        for (int p = 0; p < HPB; ++p) so += s_src[(size_t)p * HBIN];
#pragma unroll
        for (int p = 0; p < HPB; ++p) {
            const int c = s_dst[(size_t)p * HBIN];
            s_dst[(size_t)p * HBIN] = (u16)run;
            run += c;
        }
        rs_out[i] = rsqrtf(fmaxf((float)so, 1.0f));
        rs_in[i]  = rsqrtf(fmaxf((float)run, 1.0f));
        deg[i] = run;
    }
    tmp[tid] = run; __syncthreads();
    if (i < N) atomicAdd(&dh[min(run, DB - 1)], 1);
    for (int off = 1; off < 256; off <<= 1) {
        int t = (tid >= off) ? tmp[tid - off] : 0;
        __syncthreads(); tmp[tid] += t; __syncthreads();
    }
    if (i < N) partial[i] = tmp[tid];
    if (tid == 255) blocksum[blockIdx.x] = tmp[255];
    __syncthreads();
    if (tid < DB && dh[tid] > 0) atomicAdd(&degcnt[tid], dh[tid]);
}

// Fused scan2+scan3: every block redundantly scans the (<=256) block sums.
// Block 0 thread 0 also turns degcnt into exclusive degbase.
__global__ __launch_bounds__(256) void k_scan23(
    const int* __restrict__ partial, const int* __restrict__ blocksum,
    int* __restrict__ row_ptr, const int* __restrict__ degcnt,
    int* __restrict__ degbase, int n, int nb)
{
    __shared__ int tmp[256];
    const int tid = threadIdx.x;
    int v = (tid < nb) ? blocksum[tid] : 0;
    tmp[tid] = v; __syncthreads();
    for (int off = 1; off < 256; off <<= 1) {
        int t = (tid >= off) ? tmp[tid - off] : 0;
        __syncthreads(); tmp[tid] += t; __syncthreads();
    }
    __syncthreads();
    const int i = blockIdx.x * 256 + tid;
    if (i < n) {
        const int base = (blockIdx.x > 0) ? tmp[blockIdx.x - 1] : 0;
        row_ptr[i + 1] = partial[i] + base;
        if (i == 0) row_ptr[0] = 0;
    }
    if (blockIdx.x == 0 && tid == 0) {
        int run = 0;
#pragma unroll
        for (int k = 0; k < DB; ++k) { const int c = degcnt[k]; degbase[k] = run; run += c; }
    }
}

// ---------- CSR fill: LDS cursors (zero global atomics) ----------
__global__ __launch_bounds__(256) void k_fill2(
    const int* __restrict__ src, const int* __restrict__ dst,
    const int* __restrict__ row_ptr, const u16* __restrict__ slab,
    int* __restrict__ csr_src, int E, int slice, int N)
{
    __shared__ int cur[HBIN];
    const int bin = blockIdx.x / HPB;
    const int p   = blockIdx.x % HPB;
    const int lo  = bin * HBIN;

    const u16* part_off = slab + ((size_t)((HNB + bin) * HPB + p)) * HBIN;
    for (int j = threadIdx.x; j < HBIN; j += 256) {
        const int node = lo + j;
        cur[j] = (node < N) ? (row_ptr[node] + (int)part_off[j]) : 0;
    }
    __syncthreads();

    const int beg = p * slice;
    const int fin = min(beg + slice, E);
    for (int i = beg + threadIdx.x * 4; i + 3 < fin; i += 1024) {
        const int4 d = *(const int4*)(dst + i);
        const int4 s = *(const int4*)(src + i);
        int u;
        u = d.x - lo; if ((unsigned)u < (unsigned)HBIN) csr_src[atomicAdd(&cur[u], 1)] = s.x;
        u = d.y - lo; if ((unsigned)u < (unsigned)HBIN) csr_src[atomicAdd(&cur[u], 1)] = s.y;
        u = d.z - lo; if ((unsigned)u < (unsigned)HBIN) csr_src[atomicAdd(&cur[u], 1)] = s.z;
        u = d.w - lo; if ((unsigned)u < (unsigned)HBIN) csr_src[atomicAdd(&cur[u], 1)] = s.w;
    }
    for (int i = beg + ((fin - beg) & ~3) + threadIdx.x; i < fin; i += 256) {
        int u = dst[i] - lo;
        if ((unsigned)u < (unsigned)HBIN) csr_src[atomicAdd(&cur[u], 1)] = src[i];
    }
}

// ---------- degree-sorted placement: perm[pos] = node ----------
__global__ __launch_bounds__(256) void k_place(
    const int* __restrict__ deg, int* __restrict__ cursor,
    int* __restrict__ perm, int N)
{
    __shared__ int lcnt[DB];
    __shared__ int gb[DB];
    const int tid = threadIdx.x;
    const int i = blockIdx.x * 256 + tid;
    if (tid < DB) lcnt[tid] = 0;
    __syncthreads();
    int d = 0, lrank = 0;
    if (i < N) {
        d = min(deg[i], DB - 1);
        lrank = atomicAdd(&lcnt[d], 1);
    }
    __syncthreads();
    if (tid < DB) gb[tid] = (lcnt[tid] > 0) ? atomicAdd(&cursor[tid], lcnt[tid]) : 0;
    __syncthreads();
    if (i < N) perm[gb[d] + lrank] = i;
}

// ---------------- GEMM A: t1b = bf16(rs_out .* (X @ W1)) ----------------
template <int IN_F, int OUT_F, int TM>
__global__ __launch_bounds__(256) void k_gemm_bf16out(
    const float* __restrict__ X, const float* __restrict__ W,
    const float* __restrict__ rowscale, u16* __restrict__ Y, int n)
{
    constexpr int CT  = OUT_F / 4;
    constexpr int RT  = 256 / CT;
    constexpr int RPT = TM / RT;
    constexpr int XS  = IN_F + 4;
    __shared__ float sW[IN_F * OUT_F];
    __shared__ float sX[TM * XS];
    const int tid = threadIdx.x;
    const int row0 = blockIdx.x * TM;

    for (int i = tid; i < IN_F * OUT_F / 4; i += 256)
        ((float4*)sW)[i] = ((const float4*)W)[i];
    for (int i = tid; i < TM * IN_F / 4; i += 256) {
        const int r  = i / (IN_F / 4);
        const int c4 = (i % (IN_F / 4)) * 4;
        const int gr = row0 + r;
        float4 v = make_float4(0.f, 0.f, 0.f, 0.f);
        if (gr < n) v = *(const float4*)(X + (long)gr * IN_F + c4);
        *(float4*)(sX + r * XS + c4) = v;
    }
    __syncthreads();

    const int tc = tid % CT;
    const int tr = tid / CT;
    float4 acc[RPT];
#pragma unroll
    for (int i = 0; i < RPT; ++i) acc[i] = make_float4(0.f, 0.f, 0.f, 0.f);

#pragma unroll 8
    for (int k = 0; k < IN_F; ++k) {
        const float4 w = *(const float4*)(sW + k * OUT_F + 4 * tc);
#pragma unroll
        for (int i = 0; i < RPT; ++i) {
            const float xv = sX[(tr + i * RT) * XS + k];
            acc[i].x += xv * w.x; acc[i].y += xv * w.y;
            acc[i].z += xv * w.z; acc[i].w += xv * w.w;
        }
    }

#pragma unroll
    for (int i = 0; i < RPT; ++i) {
        const int gr = row0 + tr + i * RT;
        if (gr < n) {
            float4 v = acc[i];
            const float s = rowscale[gr];
            v.x *= s; v.y *= s; v.z *= s; v.w *= s;
            uint2 pk;
            pk.x = f2bf(v.x) | (f2bf(v.y) << 16);
            pk.y = f2bf(v.z) | (f2bf(v.w) << 16);
            *(uint2*)(Y + (size_t)gr * OUT_F + 4 * tc) = pk;
        }
    }
}

// ---------------- fused B: gather(t1b,64) + relu + @W2 -> t2b ----------------
__global__ __launch_bounds__(256) void k_gather_gemm_B(
    const int* __restrict__ perm,
    const int* __restrict__ row_ptr, const int* __restrict__ csr_src,
    const u16* __restrict__ t1b, const float* __restrict__ rs_in,
    const float* __restrict__ rs_out, const float* __restrict__ b1,
    const float* __restrict__ W2, u16* __restrict__ t2b, int N)
{
    __shared__ float sh[32][72];
    __shared__ float sW[64 * 32];
    __shared__ int snode[32];
    const int tid = threadIdx.x;

    for (int i = tid; i < 64 * 32 / 4; i += 256)
        ((float4*)sW)[i] = ((const float4*)W2)[i];

    const int nloc = tid / 8;
    const int gid = blockIdx.x * 32 + nloc;
    const int node = (gid < N) ? perm[gid] : -1;
    const int c8 = (tid % 8) * 8;
    if ((tid & 7) == 0) snode[nloc] = node;

    float a[8];
#pragma unroll
    for (int t = 0; t < 8; ++t) a[t] = 0.f;

    if (node >= 0) {
        const int beg = row_ptr[node];
        const int end = row_ptr[node + 1];
        int j = beg;
        for (; j + 3 < end; j += 4) {
            const int s0 = csr_src[j], s1 = csr_src[j + 1];
            const int s2 = csr_src[j + 2], s3 = csr_src[j + 3];
            const uint4 q0 = *(const uint4*)(t1b + (size_t)s0 * 64 + c8);
            const uint4 q1 = *(const uint4*)(t1b + (size_t)s1 * 64 + c8);
            const uint4 q2 = *(const uint4*)(t1b + (size_t)s2 * 64 + c8);
            const uint4 q3 = *(const uint4*)(t1b + (size_t)s3 * 64 + c8);
            a[0] += bflo(q0.x); a[1] += bfhi(q0.x); a[2] += bflo(q0.y); a[3] += bfhi(q0.y);
            a[4] += bflo(q0.z); a[5] += bfhi(q0.z); a[6] += bflo(q0.w); a[7] += bfhi(q0.w);
            a[0] += bflo(q1.x); a[1] += bfhi(q1.x); a[2] += bflo(q1.y); a[3] += bfhi(q1.y);
            a[4] += bflo(q1.z); a[5] += bfhi(q1.z); a[6] += bflo(q1.w); a[7] += bfhi(q1.w);
            a[0] += bflo(q2.x); a[1] += bfhi(q2.x); a[2] += bflo(q2.y); a[3] += bfhi(q2.y);
            a[4] += bflo(q2.z); a[5] += bfhi(q2.z); a[6] += bflo(q2.w); a[7] += bfhi(q2.w);
            a[0] += bflo(q3.x); a[1] += bfhi(q3.x); a[2] += bflo(q3.y); a[3] += bfhi(q3.y);
            a[4] += bflo(q3.z); a[5] += bfhi(q3.z); a[6] += bflo(q3.w); a[7] += bfhi(q3.w);
        }
        for (; j < end; ++j) {
            const int s = csr_src[j];
            const uint4 q = *(const uint4*)(t1b + (size_t)s * 64 + c8);
            a[0] += bflo(q.x); a[1] += bfhi(q.x); a[2] += bflo(q.y); a[3] += bfhi(q.y);
            a[4] += bflo(q.z); a[5] += bfhi(q.z); a[6] += bflo(q.w); a[7] += bfhi(q.w);
        }
        const float rs = rs_in[node];
#pragma unroll
        for (int t = 0; t < 8; ++t)
            a[t] = fmaxf(a[t] * rs + b1[c8 + t], 0.f);
    }
#pragma unroll
    for (int t = 0; t < 8; ++t) sh[nloc][c8 + t] = a[t];
    __syncthreads();

    const int n2 = tid / 8;
    const int c4 = (tid % 8) * 4;
    float4 acc = make_float4(0.f, 0.f, 0.f, 0.f);
#pragma unroll 8
    for (int k = 0; k < 64; ++k) {
        const float xv = sh[n2][k];
        const float4 w = *(const float4*)(sW + k * 32 + c4);
        acc.x += xv * w.x; acc.y += xv * w.y; acc.z += xv * w.z; acc.w += xv * w.w;
    }
    const int gn = snode[n2];
    if (gn >= 0) {
        const float s = rs_out[gn];
        uint2 pk;
        pk.x = f2bf(acc.x * s) | (f2bf(acc.y * s) << 16);
        pk.y = f2bf(acc.z * s) | (f2bf(acc.w * s) << 16);
        *(uint2*)(t2b + (size_t)gn * 32 + c4) = pk;
    }
}

// ---------------- C: gather(t2b,32) -> z (f32, d_out) + zb shadow ----------------
__global__ __launch_bounds__(256) void k_gather_C(
    const int* __restrict__ perm,
    const int* __restrict__ row_ptr, const int* __restrict__ csr_src,
    const u16* __restrict__ t2b, const float* __restrict__ rs_in,
    const float* __restrict__ rs_out, const float* __restrict__ b2,
    float* __restrict__ z, u16* __restrict__ zb, int N)
{
    const int gid = blockIdx.x * 64 + threadIdx.x / 4;
    const int c8 = (threadIdx.x % 4) * 8;
    if (gid >= N) return;
    const int node = perm[gid];

    const int beg = row_ptr[node];
    const int end = row_ptr[node + 1];
    float a[8];
#pragma unroll
    for (int t = 0; t < 8; ++t) a[t] = 0.f;

    int j = beg;
    for (; j + 3 < end; j += 4) {
        const int s0 = csr_src[j], s1 = csr_src[j + 1];
        const int s2 = csr_src[j + 2], s3 = csr_src[j + 3];
        const uint4 q0 = *(const uint4*)(t2b + (size_t)s0 * 32 + c8);
        const uint4 q1 = *(const uint4*)(t2b + (size_t)s1 * 32 + c8);
        const uint4 q2 = *(const uint4*)(t2b + (size_t)s2 * 32 + c8);
        const uint4 q3 = *(const uint4*)(t2b + (size_t)s3 * 32 + c8);
        a[0] += bflo(q0.x); a[1] += bfhi(q0.x); a[2] += bflo(q0.y); a[3] += bfhi(q0.y);
        a[4] += bflo(q0.z); a[5] += bfhi(q0.z); a[6] += bflo(q0.w); a[7] += bfhi(q0.w);
        a[0] += bflo(q1.x); a[1] += bfhi(q1.x); a[2] += bflo(q1.y); a[3] += bfhi(q1.y);
        a[4] += bflo(q1.z); a[5] += bfhi(q1.z); a[6] += bflo(q1.w); a[7] += bfhi(q1.w);
        a[0] += bflo(q2.x); a[1] += bfhi(q2.x); a[2] += bflo(q2.y); a[3] += bfhi(q2.y);
        a[4] += bflo(q2.z); a[5] += bfhi(q2.z); a[6] += bflo(q2.w); a[7] += bfhi(q2.w);
        a[0] += bflo(q3.x); a[1] += bfhi(q3.x); a[2] += bflo(q3.y); a[3] += bfhi(q3.y);
        a[4] += bflo(q3.z); a[5] += bfhi(q3.z); a[6] += bflo(q3.w); a[7] += bfhi(q3.w);
    }
    for (; j < end; ++j) {
        const int s = csr_src[j];
        const uint4 q = *(const uint4*)(t2b + (size_t)s * 32 + c8);
        a[0] += bflo(q.x); a[1] += bfhi(q.x); a[2] += bflo(q.y); a[3] += bfhi(q.y);
        a[4] += bflo(q.z); a[5] += bfhi(q.z); a[6] += bflo(q.w); a[7] += bfhi(q.w);
    }

    const float rs = rs_in[node];
    float v[8];
#pragma unroll
    for (int t = 0; t < 8; ++t) v[t] = a[t] * rs + b2[c8 + t];

    float* o = z + (size_t)node * 32 + c8;
    *(float4*)(o)     = make_float4(v[0], v[1], v[2], v[3]);
    *(float4*)(o + 4) = make_float4(v[4], v[5], v[6], v[7]);

    const float ss = rs_out[node];
    uint4 pk;
    pk.x = f2bf(v[0] * ss) | (f2bf(v[1] * ss) << 16);
    pk.y = f2bf(v[2] * ss) | (f2bf(v[3] * ss) << 16);
    pk.z = f2bf(v[4] * ss) | (f2bf(v[5] * ss) << 16);
    pk.w = f2bf(v[6] * ss) | (f2bf(v[7] * ss) << 16);
    *(uint4*)(zb + (size_t)node * 32 + c8) = pk;
}

// ---------------- fused D: gather(zb,32) + @W3 + b3 -> recon ----------------
__global__ __launch_bounds__(256) void k_gather_gemm_D(
    const int* __restrict__ perm,
    const int* __restrict__ row_ptr, const int* __restrict__ csr_src,
    const u16* __restrict__ zb, const float* __restrict__ rs_in,
    const float* __restrict__ W3, const float* __restrict__ b3,
    float* __restrict__ recon, int N)
{
    __shared__ float sa[64][36];
    __shared__ float sW[32 * 128];
    __shared__ int snode[64];
    const int tid = threadIdx.x;

    for (int i = tid; i < 32 * 128 / 4; i += 256)
        ((float4*)sW)[i] = ((const float4*)W3)[i];

    const int nloc = tid / 4;
    const int gid = blockIdx.x * 64 + nloc;
    const int node = (gid < N) ? perm[gid] : -1;
    const int c8 = (tid % 4) * 8;
    if ((tid & 3) == 0) snode[nloc] = node;

    float a[8];
#pragma unroll
    for (int t = 0; t < 8; ++t) a[t] = 0.f;

    if (node >= 0) {
        const int beg = row_ptr[node];
        const int end = row_ptr[node + 1];
        int j = beg;
        for (; j + 3 < end; j += 4) {
            const int s0 = csr_src[j], s1 = csr_src[j + 1];
            const int s2 = csr_src[j + 2], s3 = csr_src[j + 3];
            const uint4 q0 = *(const uint4*)(zb + (size_t)s0 * 32 + c8);
            const uint4 q1 = *(const uint4*)(zb + (size_t)s1 * 32 + c8);
            const uint4 q2 = *(const uint4*)(zb + (size_t)s2 * 32 + c8);
            const uint4 q3 = *(const uint4*)(zb + (size_t)s3 * 32 + c8);
            a[0] += bflo(q0.x); a[1] += bfhi(q0.x); a[2] += bflo(q0.y); a[3] += bfhi(q0.y);
            a[4] += bflo(q0.z); a[5] += bfhi(q0.z); a[6] += bflo(q0.w); a[7] += bfhi(q0.w);
            a[0] += bflo(q1.x); a[1] += bfhi(q1.x); a[2] += bflo(q1.y); a[3] += bfhi(q1.y);
            a[4] += bflo(q1.z); a[5] += bfhi(q1.z); a[6] += bflo(q1.w); a[7] += bfhi(q1.w);
            a[0] += bflo(q2.x); a[1] += bfhi(q2.x); a[2] += bflo(q2.y); a[3] += bfhi(q2.y);
            a[4] += bflo(q2.z); a[5] += bfhi(q2.z); a[6] += bflo(q2.w); a[7] += bfhi(q2.w);
            a[0] += bflo(q3.x); a[1] += bfhi(q3.x); a[2] += bflo(q3.y); a[3] += bfhi(q3.y);
            a[4] += bflo(q3.z); a[5] += bfhi(q3.z); a[6] += bflo(q3.w); a[7] += bfhi(q3.w);
        }
        for (; j < end; ++j) {
            const int s = csr_src[j];
            const uint4 q = *(const uint4*)(zb + (size_t)s * 32 + c8);
            a[0] += bflo(q.x); a[1] += bfhi(q.x); a[2] += bflo(q.y); a[3] += bfhi(q.y);
            a[4] += bflo(q.z); a[5] += bfhi(q.z); a[6] += bflo(q.w); a[7] += bfhi(q.w);
        }
        const float rs = rs_in[node];
#pragma unroll
        for (int t = 0; t < 8; ++t) a[t] *= rs;
    }
#pragma unroll
    for (int t = 0; t < 8; ++t) sa[nloc][c8 + t] = a[t];
    __syncthreads();

    const int ng = (tid / 32) * 8;
    const int c4 = (tid % 32) * 4;
    const float4 bb = *(const float4*)(b3 + c4);
    float4 acc[8];
#pragma unroll
    for (int i = 0; i < 8; ++i) acc[i] = bb;
#pragma unroll 4
    for (int k = 0; k < 32; ++k) {
        const float4 w = *(const float4*)(sW + k * 128 + c4);
#pragma unroll
        for (int i = 0; i < 8; ++i) {
            const float xv = sa[ng + i][k];
            acc[i].x += xv * w.x; acc[i].y += xv * w.y;
            acc[i].z += xv * w.z; acc[i].w += xv * w.w;
        }
    }
#pragma unroll
    for (int i = 0; i < 8; ++i) {
        const int gn = snode[ng + i];
        if (gn >= 0) *(float4*)(recon + (size_t)gn * 128 + c4) = acc[i];
    }
}

extern "C" void kernel_launch(void* const* d_in, const int* in_sizes, int n_in,
                              void* d_out, int out_size, void* d_ws, size_t ws_size,
                              hipStream_t stream) {
    const float* feat = (const float*)d_in[0];   // [N,128]
    const int*   src  = (const int*)d_in[1];     // [E]
    const int*   dst  = (const int*)d_in[2];     // [E]
    const float* W1   = (const float*)d_in[3];   // [128,64]
    const float* b1   = (const float*)d_in[4];   // [64]
    const float* W2   = (const float*)d_in[5];   // [64,32]
    const float* b2   = (const float*)d_in[6];   // [32]
    const float* W3   = (const float*)d_in[7];   // [32,128]
    const float* b3   = (const float*)d_in[8];   // [128]

    const int E = in_sizes[1];
    const int N = in_sizes[0] / 128;             // 50000 == HNB*HBIN
    const int slice = (((E + HPB - 1) / HPB) + 3) & ~3;

    // ---- workspace layout (16B alignment at every boundary) ----
    const size_t SLABN = 2UL * HNB * HPB * HBIN;  // 6.4M u16 = 12.8MB
    u16* slab     = (u16*)d_ws;                   // dead after k_fill2
    int* row_ptr  = (int*)(slab + SLABN);         // [N+16]
    int* scan_p   = row_ptr + N + 16;             // [N]
    int* blocksum = scan_p + N;                   // [256]
    int* degcnt   = blocksum + 256;               // [DB]
    int* degbase  = degcnt + DB;                  // [DB] (cursor in k_place)
    int* deg      = degbase + DB;                 // [N]
    int* perm     = deg + N;                      // [N]
    int* csr_src  = perm + N;                     // [E]
    float* rs_out = (float*)(csr_src + E);        // [N]
    float* rs_in  = rs_out + N;                   // [N]
    u16* t2b      = (u16*)(rs_in + N);            // [N,32] bf16
    u16* zb       = t2b + (size_t)N * 32;         // [N,32] bf16 (z * rs_out)
    u16* t1b      = (u16*)slab;                   // [N,64] bf16, aliases dead slab

    float* z_out  = (float*)d_out;                // [N,32]
    float* recon  = z_out + (size_t)N * 32;       // [N,128]

    const int B = 256;
    const int nb_scan = (N + 255) / 256;          // 196

    // ---- atomic-light graph preprocessing ----
    k_hist2<<<2 * HNB * HPB, B, 0, stream>>>(src, dst, slab, degcnt, E, slice);
    k_reduce_scan<<<nb_scan, B, 0, stream>>>(slab, rs_out, rs_in, scan_p, blocksum,
                                             deg, degcnt, N);
    k_scan23<<<nb_scan, B, 0, stream>>>(scan_p, blocksum, row_ptr, degcnt, degbase,
                                        N, nb_scan);
    k_fill2<<<HNB * HPB, B, 0, stream>>>(src, dst, row_ptr, slab, csr_src, E, slice, N);
    k_place<<<nb_scan, B, 0, stream>>>(deg, degbase, perm, N);

    // ---- A: t1b = bf16(rs_out .* (X @ W1)) (overwrites slab after fill) ----
    k_gemm_bf16out<128, 64, 32><<<(N + 31) / 32, B, 0, stream>>>(
        feat, W1, rs_out, t1b, N);

    // ---- B: gather(t1b) + relu + @W2 -> t2b ----
    k_gather_gemm_B<<<(N + 31) / 32, B, 0, stream>>>(
        perm, row_ptr, csr_src, t1b, rs_in, rs_out, b1, W2, t2b, N);

    // ---- C: gather(t2b) -> z (d_out) + zb shadow ----
    k_gather_C<<<(N + 63) / 64, B, 0, stream>>>(
        perm, row_ptr, csr_src, t2b, rs_in, rs_out, b2, z_out, zb, N);

    // ---- D: gather(zb) + @W3 + b3 -> recon ----
    k_gather_gemm_D<<<(N + 63) / 64, B, 0, stream>>>(
        perm, row_ptr, csr_src, zb, rs_in, W3, b3, recon, N);
}

// Round 8
// 202.475 us; speedup vs baseline: 1.0761x; 1.0761x over previous
//
#include <hip/hip_runtime.h>
#include <hip/hip_bf16.h>

// GraphAutoencoder: 3x GraphConv (DGL norm='both') on fixed graph.
// N=50000 nodes, E=600000 edges, widths 128 -> 64 -> 32 -> 128.
//
// R1: scatter-atomics RMW-bound (485us). R2: CSR+gather -> 340us.
// R3: tiled GEMM/gathers -> 277us (LDS hist regressed: 128 blocks / 4.7% occ).
// R4: atomic-free counting sort -> 243us. (harness 0xAA poison of 256MiB ws
//     = fixed ~44us inside timed window; controllable budget ~170us)
// R5: bf16 gather sources + zb shadow -> 223us. R6: row-local fusion -> 213us.
// R7: degree-sort perm REGRESSED (218us): broke row_ptr/csr_src streaming
//     locality + scattered writes + extra kernel. Reverted.
// R8: (a) 2-way edge-split gathers: half-groups walk half the edge list,
//     combine via shfl_xor -> sequential load-chain ~1.5x shorter, 2x MLP.
//     (b) hist: HNB=1, packed-u16 LDS counts (100KB), HPB=128 -> 256 blocks,
//     edge arrays read once (19.2->4.8MB). k_place/perm deleted.
//
// Pipeline:
//   A: t1b = bf16(rs_out .* (X @ W1))                      [GEMM]
//   B: agg=gather(t1b); h=relu(rs_in*agg+b1);
//      t2b = bf16(rs_out .* (h @ W2))                      [fused]
//   C: z = rs_in*gather(t2b)+b2 -> d_out; zb = bf16(z*rs_out)
//   D: recon = (rs_in .* gather(zb)) @ W3 + b3 -> d_out    [fused]

#define NN   50000     // nodes (fixed)
#define HPB  128       // edge partitions
#define FNB  4         // fill node bins
#define FBIN 12500     // nodes per fill bin
typedef unsigned short u16;

__device__ __forceinline__ float bfhi(unsigned u) {
    unsigned v = u & 0xFFFF0000u;
    return __builtin_bit_cast(float, v);
}
__device__ __forceinline__ float bflo(unsigned u) {
    unsigned v = u << 16;
    return __builtin_bit_cast(float, v);
}
__device__ __forceinline__ unsigned f2bf(float f) {   // f32 -> bf16 RNE
    unsigned u = __builtin_bit_cast(unsigned, f);
    return (u + 0x7FFFu + ((u >> 16) & 1u)) >> 16;
}

// ---------------- histogram: u16 slab[2][HPB][NN], packed-u16 LDS ----------------
// Per-partition counts <= slice (4688) < 65536 -> packed halves never overflow.
__global__ __launch_bounds__(256) void k_hist1(
    const int* __restrict__ src, const int* __restrict__ dst,
    u16* __restrict__ slab, int E, int slice)
{
    __shared__ unsigned h[NN / 2];               // 100KB
    const int which = blockIdx.x / HPB;          // 0: src, 1: dst
    const int p     = blockIdx.x % HPB;
    const int* __restrict__ idx = which ? dst : src;

    for (int i = threadIdx.x; i < NN / 2; i += 256) h[i] = 0;
    __syncthreads();

    const int beg = p * slice;
    const int fin = min(beg + slice, E);
    for (int i = beg + threadIdx.x * 4; i + 3 < fin; i += 1024) {
        const int4 v = *(const int4*)(idx + i);
        atomicAdd(&h[v.x >> 1], 1u << ((v.x & 1) << 4));
        atomicAdd(&h[v.y >> 1], 1u << ((v.y & 1) << 4));
        atomicAdd(&h[v.z >> 1], 1u << ((v.z & 1) << 4));
        atomicAdd(&h[v.w >> 1], 1u << ((v.w & 1) << 4));
    }
    for (int i = beg + ((fin - beg) & ~3) + threadIdx.x; i < fin; i += 256) {
        const int u = idx[i];
        atomicAdd(&h[u >> 1], 1u << ((u & 1) << 4));
    }
    __syncthreads();

    unsigned* out = (unsigned*)(slab + (size_t)blockIdx.x * NN);
    for (int i = threadIdx.x; i < NN / 2; i += 256) out[i] = h[i];
}

// degrees -> rsqrt; dst half -> per-partition exclusive offsets (in place);
// block-level inclusive scan of in-degree (fused scan1).
__global__ __launch_bounds__(256) void k_reduce_scan(
    u16* __restrict__ slab, float* __restrict__ rs_out, float* __restrict__ rs_in,
    int* __restrict__ partial, int* __restrict__ blocksum, int N)
{
    __shared__ int tmp[256];
    const int tid = threadIdx.x;
    const int i = blockIdx.x * 256 + tid;

    int run = 0;
    if (i < N) {
        const u16* s_src = slab + i;
        u16*       s_dst = slab + (size_t)HPB * NN + i;
        int so = 0;
#pragma unroll 8
        for (int p = 0; p < HPB; ++p) so += s_src[(size_t)p * NN];
#pragma unroll 8
        for (int p = 0; p < HPB; ++p) {
            const int c = s_dst[(size_t)p * NN];
            s_dst[(size_t)p * NN] = (u16)run;
            run += c;
        }
        rs_out[i] = rsqrtf(fmaxf((float)so, 1.0f));
        rs_in[i]  = rsqrtf(fmaxf((float)run, 1.0f));
    }
    tmp[tid] = run; __syncthreads();
    for (int off = 1; off < 256; off <<= 1) {
        int t = (tid >= off) ? tmp[tid - off] : 0;
        __syncthreads(); tmp[tid] += t; __syncthreads();
    }
    if (i < N) partial[i] = tmp[tid];
    if (tid == 255) blocksum[blockIdx.x] = tmp[255];
}

// Fused scan2+scan3: every block redundantly scans the (<=256) block sums.
__global__ __launch_bounds__(256) void k_scan23(
    const int* __restrict__ partial, const int* __restrict__ blocksum,
    int* __restrict__ row_ptr, int n, int nb)
{
    __shared__ int tmp[256];
    const int tid = threadIdx.x;
    int v = (tid < nb) ? blocksum[tid] : 0;
    tmp[tid] = v; __syncthreads();
    for (int off = 1; off < 256; off <<= 1) {
        int t = (tid >= off) ? tmp[tid - off] : 0;
        __syncthreads(); tmp[tid] += t; __syncthreads();
    }
    __syncthreads();
    const int i = blockIdx.x * 256 + tid;
    if (i < n) {
        const int base = (blockIdx.x > 0) ? tmp[blockIdx.x - 1] : 0;
        row_ptr[i + 1] = partial[i] + base;
        if (i == 0) row_ptr[0] = 0;
    }
}

// ---------- CSR fill: LDS cursors (zero global atomics) ----------
__global__ __launch_bounds__(256) void k_fill2(
    const int* __restrict__ src, const int* __restrict__ dst,
    const int* __restrict__ row_ptr, const u16* __restrict__ slab,
    int* __restrict__ csr_src, int E, int slice, int N)
{
    __shared__ int cur[FBIN];
    const int bin = blockIdx.x / HPB;
    const int p   = blockIdx.x % HPB;
    const int lo  = bin * FBIN;

    const u16* part_off = slab + (size_t)(HPB + p) * NN;   // dst half, partition p
    for (int j = threadIdx.x; j < FBIN; j += 256) {
        const int node = lo + j;
        cur[j] = (node < N) ? (row_ptr[node] + (int)part_off[node]) : 0;
    }
    __syncthreads();

    const int beg = p * slice;
    const int fin = min(beg + slice, E);
    for (int i = beg + threadIdx.x * 4; i + 3 < fin; i += 1024) {
        const int4 d = *(const int4*)(dst + i);
        const int4 s = *(const int4*)(src + i);
        int u;
        u = d.x - lo; if ((unsigned)u < (unsigned)FBIN) csr_src[atomicAdd(&cur[u], 1)] = s.x;
        u = d.y - lo; if ((unsigned)u < (unsigned)FBIN) csr_src[atomicAdd(&cur[u], 1)] = s.y;
        u = d.z - lo; if ((unsigned)u < (unsigned)FBIN) csr_src[atomicAdd(&cur[u], 1)] = s.z;
        u = d.w - lo; if ((unsigned)u < (unsigned)FBIN) csr_src[atomicAdd(&cur[u], 1)] = s.w;
    }
    for (int i = beg + ((fin - beg) & ~3) + threadIdx.x; i < fin; i += 256) {
        int u = dst[i] - lo;
        if ((unsigned)u < (unsigned)FBIN) csr_src[atomicAdd(&cur[u], 1)] = src[i];
    }
}

// ---------------- GEMM A: t1b = bf16(rs_out .* (X @ W1)) ----------------
template <int IN_F, int OUT_F, int TM>
__global__ __launch_bounds__(256) void k_gemm_bf16out(
    const float* __restrict__ X, const float* __restrict__ W,
    const float* __restrict__ rowscale, u16* __restrict__ Y, int n)
{
    constexpr int CT  = OUT_F / 4;
    constexpr int RT  = 256 / CT;
    constexpr int RPT = TM / RT;
    constexpr int XS  = IN_F + 4;
    __shared__ float sW[IN_F * OUT_F];
    __shared__ float sX[TM * XS];
    const int tid = threadIdx.x;
    const int row0 = blockIdx.x * TM;

    for (int i = tid; i < IN_F * OUT_F / 4; i += 256)
        ((float4*)sW)[i] = ((const float4*)W)[i];
    for (int i = tid; i < TM * IN_F / 4; i += 256) {
        const int r  = i / (IN_F / 4);
        const int c4 = (i % (IN_F / 4)) * 4;
        const int gr = row0 + r;
        float4 v = make_float4(0.f, 0.f, 0.f, 0.f);
        if (gr < n) v = *(const float4*)(X + (long)gr * IN_F + c4);
        *(float4*)(sX + r * XS + c4) = v;
    }
    __syncthreads();

    const int tc = tid % CT;
    const int tr = tid / CT;
    float4 acc[RPT];
#pragma unroll
    for (int i = 0; i < RPT; ++i) acc[i] = make_float4(0.f, 0.f, 0.f, 0.f);

#pragma unroll 8
    for (int k = 0; k < IN_F; ++k) {
        const float4 w = *(const float4*)(sW + k * OUT_F + 4 * tc);
#pragma unroll
        for (int i = 0; i < RPT; ++i) {
            const float xv = sX[(tr + i * RT) * XS + k];
            acc[i].x += xv * w.x; acc[i].y += xv * w.y;
            acc[i].z += xv * w.z; acc[i].w += xv * w.w;
        }
    }

#pragma unroll
    for (int i = 0; i < RPT; ++i) {
        const int gr = row0 + tr + i * RT;
        if (gr < n) {
            float4 v = acc[i];
            const float s = rowscale[gr];
            v.x *= s; v.y *= s; v.z *= s; v.w *= s;
            uint2 pk;
            pk.x = f2bf(v.x) | (f2bf(v.y) << 16);
            pk.y = f2bf(v.z) | (f2bf(v.w) << 16);
            *(uint2*)(Y + (size_t)gr * OUT_F + 4 * tc) = pk;
        }
    }
}

// accumulate one bf16x8 row chunk
#define ACC8(q) do { \
    a[0] += bflo((q).x); a[1] += bfhi((q).x); a[2] += bflo((q).y); a[3] += bfhi((q).y); \
    a[4] += bflo((q).z); a[5] += bfhi((q).z); a[6] += bflo((q).w); a[7] += bfhi((q).w); } while (0)

// ---------------- fused B: gather(t1b,64) + relu + @W2 -> t2b ----------------
// 16 lanes/node: 8 col-lanes x 2 edge-halves; halves combine via shfl_xor(8).
__global__ __launch_bounds__(256) void k_gather_gemm_B(
    const int* __restrict__ row_ptr, const int* __restrict__ csr_src,
    const u16* __restrict__ t1b, const float* __restrict__ rs_in,
    const float* __restrict__ rs_out, const float* __restrict__ b1,
    const float* __restrict__ W2, u16* __restrict__ t2b, int N)
{
    __shared__ float sh[16][72];
    __shared__ float sW[64 * 32];
    const int tid = threadIdx.x;

    for (int i = tid; i < 64 * 32 / 4; i += 256)
        ((float4*)sW)[i] = ((const float4*)W2)[i];

    const int nloc = tid >> 4;           // 16 nodes/block
    const int sub  = tid & 15;
    const int half = sub >> 3;
    const int c8   = (sub & 7) * 8;
    const int node = blockIdx.x * 16 + nloc;

    float a[8];
#pragma unroll
    for (int t = 0; t < 8; ++t) a[t] = 0.f;

    if (node < N) {
        const int beg = row_ptr[node];
        const int end = row_ptr[node + 1];
        const int len0 = (end - beg + 1) >> 1;
        int j        = half ? beg + len0 : beg;
        const int je = half ? end : beg + len0;
        for (; j + 3 < je; j += 4) {
            const int s0 = csr_src[j], s1 = csr_src[j + 1];
            const int s2 = csr_src[j + 2], s3 = csr_src[j + 3];
            const uint4 q0 = *(const uint4*)(t1b + (size_t)s0 * 64 + c8);
            const uint4 q1 = *(const uint4*)(t1b + (size_t)s1 * 64 + c8);
            const uint4 q2 = *(const uint4*)(t1b + (size_t)s2 * 64 + c8);
            const uint4 q3 = *(const uint4*)(t1b + (size_t)s3 * 64 + c8);
            ACC8(q0); ACC8(q1); ACC8(q2); ACC8(q3);
        }
        for (; j < je; ++j) {
            const uint4 q = *(const uint4*)(t1b + (size_t)csr_src[j] * 64 + c8);
            ACC8(q);
        }
    }
#pragma unroll
    for (int t = 0; t < 8; ++t) a[t] += __shfl_xor(a[t], 8);

    if (node < N && half == 0) {
        const float rs = rs_in[node];
#pragma unroll
        for (int t = 0; t < 8; ++t)
            sh[nloc][c8 + t] = fmaxf(a[t] * rs + b1[c8 + t], 0.f);
    }
    __syncthreads();

    if (tid < 128) {                      // 16 nodes x 8 float4-cols
        const int n2 = tid >> 3;
        const int c4 = (tid & 7) * 4;
        float4 acc = make_float4(0.f, 0.f, 0.f, 0.f);
#pragma unroll 8
        for (int k = 0; k < 64; ++k) {
            const float xv = sh[n2][k];
            const float4 w = *(const float4*)(sW + k * 32 + c4);
            acc.x += xv * w.x; acc.y += xv * w.y; acc.z += xv * w.z; acc.w += xv * w.w;
        }
        const int gn = blockIdx.x * 16 + n2;
        if (gn < N) {
            const float s = rs_out[gn];
            uint2 pk;
            pk.x = f2bf(acc.x * s) | (f2bf(acc.y * s) << 16);
            pk.y = f2bf(acc.z * s) | (f2bf(acc.w * s) << 16);
            *(uint2*)(t2b + (size_t)gn * 32 + c4) = pk;
        }
    }
}

// ---------------- C: gather(t2b,32) -> z (f32, d_out) + zb shadow ----------------
// 8 lanes/node: 4 col-lanes x 2 edge-halves; combine via shfl_xor(4).
__global__ __launch_bounds__(256) void k_gather_C(
    const int* __restrict__ row_ptr, const int* __restrict__ csr_src,
    const u16* __restrict__ t2b, const float* __restrict__ rs_in,
    const float* __restrict__ rs_out, const float* __restrict__ b2,
    float* __restrict__ z, u16* __restrict__ zb, int N)
{
    const int node = blockIdx.x * 32 + (threadIdx.x >> 3);
    const int sub  = threadIdx.x & 7;
    const int half = sub >> 2;
    const int c8   = (sub & 3) * 8;
    if (node >= N) return;               // whole 8-lane group exits together

    const int beg = row_ptr[node];
    const int end = row_ptr[node + 1];
    const int len0 = (end - beg + 1) >> 1;
    int j        = half ? beg + len0 : beg;
    const int je = half ? end : beg + len0;

    float a[8];
#pragma unroll
    for (int t = 0; t < 8; ++t) a[t] = 0.f;

    for (; j + 3 < je; j += 4) {
        const int s0 = csr_src[j], s1 = csr_src[j + 1];
        const int s2 = csr_src[j + 2], s3 = csr_src[j + 3];
        const uint4 q0 = *(const uint4*)(t2b + (size_t)s0 * 32 + c8);
        const uint4 q1 = *(const uint4*)(t2b + (size_t)s1 * 32 + c8);
        const uint4 q2 = *(const uint4*)(t2b + (size_t)s2 * 32 + c8);
        const uint4 q3 = *(const uint4*)(t2b + (size_t)s3 * 32 + c8);
        ACC8(q0); ACC8(q1); ACC8(q2); ACC8(q3);
    }
    for (; j < je; ++j) {
        const uint4 q = *(const uint4*)(t2b + (size_t)csr_src[j] * 32 + c8);
        ACC8(q);
    }
#pragma unroll
    for (int t = 0; t < 8; ++t) a[t] += __shfl_xor(a[t], 4);
    if (half) return;

    const float rs = rs_in[node];
    float v[8];
#pragma unroll
    for (int t = 0; t < 8; ++t) v[t] = a[t] * rs + b2[c8 + t];

    float* o = z + (size_t)node * 32 + c8;
    *(float4*)(o)     = make_float4(v[0], v[1], v[2], v[3]);
    *(float4*)(o + 4) = make_float4(v[4], v[5], v[6], v[7]);

    const float ss = rs_out[node];
    uint4 pk;
    pk.x = f2bf(v[0] * ss) | (f2bf(v[1] * ss) << 16);
    pk.y = f2bf(v[2] * ss) | (f2bf(v[3] * ss) << 16);
    pk.z = f2bf(v[4] * ss) | (f2bf(v[5] * ss) << 16);
    pk.w = f2bf(v[6] * ss) | (f2bf(v[7] * ss) << 16);
    *(uint4*)(zb + (size_t)node * 32 + c8) = pk;
}

// ---------------- fused D: gather(zb,32) + @W3 + b3 -> recon ----------------
// 8 lanes/node x 32 nodes/block; edge-halves combine via shfl_xor(4).
__global__ __launch_bounds__(256) void k_gather_gemm_D(
    const int* __restrict__ row_ptr, const int* __restrict__ csr_src,
    const u16* __restrict__ zb, const float* __restrict__ rs_in,
    const float* __restrict__ W3, const float* __restrict__ b3,
    float* __restrict__ recon, int N)
{
    __shared__ float sa[32][36];
    __shared__ float sW[32 * 128];
    const int tid = threadIdx.x;

    for (int i = tid; i < 32 * 128 / 4; i += 256)
        ((float4*)sW)[i] = ((const float4*)W3)[i];

    const int nloc = tid >> 3;
    const int sub  = tid & 7;
    const int half = sub >> 2;
    const int c8   = (sub & 3) * 8;
    const int node = blockIdx.x * 32 + nloc;

    float a[8];
#pragma unroll
    for (int t = 0; t < 8; ++t) a[t] = 0.f;

    if (node < N) {
        const int beg = row_ptr[node];
        const int end = row_ptr[node + 1];
        const int len0 = (end - beg + 1) >> 1;
        int j        = half ? beg + len0 : beg;
        const int je = half ? end : beg + len0;
        for (; j + 3 < je; j += 4) {
            const int s0 = csr_src[j], s1 = csr_src[j + 1];
            const int s2 = csr_src[j + 2], s3 = csr_src[j + 3];
            const uint4 q0 = *(const uint4*)(zb + (size_t)s0 * 32 + c8);
            const uint4 q1 = *(const uint4*)(zb + (size_t)s1 * 32 + c8);
            const uint4 q2 = *(const uint4*)(zb + (size_t)s2 * 32 + c8);
            const uint4 q3 = *(const uint4*)(zb + (size_t)s3 * 32 + c8);
            ACC8(q0); ACC8(q1); ACC8(q2); ACC8(q3);
        }
        for (; j < je; ++j) {
            const uint4 q = *(const uint4*)(zb + (size_t)csr_src[j] * 32 + c8);
            ACC8(q);
        }
    }
#pragma unroll
    for (int t = 0; t < 8; ++t) a[t] += __shfl_xor(a[t], 4);

    if (node < N && half == 0) {
        const float rs = rs_in[node];
#pragma unroll
        for (int t = 0; t < 8; ++t) sa[nloc][c8 + t] = a[t] * rs;
    }
    __syncthreads();

    // GEMM: 32 nodes x 128 cols; thread -> 4 nodes x 4 cols
    const int ng = (tid >> 5) * 4;
    const int c4 = (tid & 31) * 4;
    const float4 bb = *(const float4*)(b3 + c4);
    float4 acc[4];
#pragma unroll
    for (int i = 0; i < 4; ++i) acc[i] = bb;
#pragma unroll 4
    for (int k = 0; k < 32; ++k) {
        const float4 w = *(const float4*)(sW + k * 128 + c4);
#pragma unroll
        for (int i = 0; i < 4; ++i) {
            const float xv = sa[ng + i][k];
            acc[i].x += xv * w.x; acc[i].y += xv * w.y;
            acc[i].z += xv * w.z; acc[i].w += xv * w.w;
        }
    }
#pragma unroll
    for (int i = 0; i < 4; ++i) {
        const int gn = blockIdx.x * 32 + ng + i;
        if (gn < N) *(float4*)(recon + (size_t)gn * 128 + c4) = acc[i];
    }
}

extern "C" void kernel_launch(void* const* d_in, const int* in_sizes, int n_in,
                              void* d_out, int out_size, void* d_ws, size_t ws_size,
                              hipStream_t stream) {
    const float* feat = (const float*)d_in[0];   // [N,128]
    const int*   src  = (const int*)d_in[1];     // [E]
    const int*   dst  = (const int*)d_in[2];     // [E]
    const float* W1   = (const float*)d_in[3];   // [128,64]
    const float* b1   = (const float*)d_in[4];   // [64]
    const float* W2   = (const float*)d_in[5];   // [64,32]
    const float* b2   = (const float*)d_in[6];   // [32]
    const float* W3   = (const float*)d_in[7];   // [32,128]
    const float* b3   = (const float*)d_in[8];   // [128]

    const int E = in_sizes[1];
    const int N = in_sizes[0] / 128;             // 50000 == NN
    const int slice = (((E + HPB - 1) / HPB) + 3) & ~3;

    // ---- workspace layout (16B alignment at every boundary) ----
    const size_t SLABN = 2UL * HPB * NN;          // 12.8M u16 = 25.6MB
    u16* slab     = (u16*)d_ws;                   // dead after k_fill2
    int* row_ptr  = (int*)(slab + SLABN);         // [N+16]
    int* scan_p   = row_ptr + N + 16;             // [N]
    int* blocksum = scan_p + N;                   // [256]
    int* csr_src  = blocksum + 256;               // [E]
    float* rs_out = (float*)(csr_src + E);        // [N]
    float* rs_in  = rs_out + N;                   // [N]
    u16* t2b      = (u16*)(rs_in + N);            // [N,32] bf16
    u16* zb       = t2b + (size_t)N * 32;         // [N,32] bf16 (z * rs_out)
    u16* t1b      = (u16*)slab;                   // [N,64] bf16, aliases dead slab

    float* z_out  = (float*)d_out;                // [N,32]
    float* recon  = z_out + (size_t)N * 32;       // [N,128]

    const int B = 256;
    const int nb_scan = (N + 255) / 256;          // 196

    // ---- atomic-free graph preprocessing ----
    k_hist1<<<2 * HPB, B, 0, stream>>>(src, dst, slab, E, slice);
    k_reduce_scan<<<nb_scan, B, 0, stream>>>(slab, rs_out, rs_in, scan_p, blocksum, N);
    k_scan23<<<nb_scan, B, 0, stream>>>(scan_p, blocksum, row_ptr, N, nb_scan);
    k_fill2<<<FNB * HPB, B, 0, stream>>>(src, dst, row_ptr, slab, csr_src, E, slice, N);

    // ---- A: t1b = bf16(rs_out .* (X @ W1)) (overwrites slab after fill) ----
    k_gemm_bf16out<128, 64, 32><<<(N + 31) / 32, B, 0, stream>>>(
        feat, W1, rs_out, t1b, N);

    // ---- B: gather(t1b) + relu + @W2 -> t2b ----
    k_gather_gemm_B<<<(N + 15) / 16, B, 0, stream>>>(
        row_ptr, csr_src, t1b, rs_in, rs_out, b1, W2, t2b, N);

    // ---- C: gather(t2b) -> z (d_out) + zb shadow ----
    k_gather_C<<<(N + 31) / 32, B, 0, stream>>>(
        row_ptr, csr_src, t2b, rs_in, rs_out, b2, z_out, zb, N);

    // ---- D: gather(zb) + @W3 + b3 -> recon ----
    k_gather_gemm_D<<<(N + 31) / 32, B, 0, stream>>>(
        row_ptr, csr_src, zb, rs_in, W3, b3, recon, N);
}

// Round 9
// 190.903 us; speedup vs baseline: 1.1413x; 1.0606x over previous
//
#include <hip/hip_runtime.h>
#include <hip/hip_bf16.h>

// GraphAutoencoder: 3x GraphConv (DGL norm='both') on fixed graph.
// N=50000 nodes, E=600000 edges, widths 128 -> 64 -> 32 -> 128.
//
// R1: scatter-atomics RMW-bound (485us). R2: CSR+gather -> 340us.
// R3: tiled GEMM/gathers -> 277us. R4: atomic-free counting sort -> 243us.
//     (harness 0xAA poison of 256MiB ws = fixed ~43us in the timed window)
// R5: bf16 gather sources + zb shadow -> 223us. R6: row-local fusion -> 213us.
// R7: degree-sort perm REGRESSED (locality). R8: 2-way edge-split + packed
//     LDS hist -> 202us. Gathers are sequential-LATENCY bound (BW would be
//     ~8us), ~3 dependent rounds per node.
// R9: pad each node's edge list to mult-of-16, 4-way edge split -> exactly
//     ~1 four-unrolled round per quarter (no remainder, no masks). Dummy
//     slots -> zero row at id N (exact +0.0). u8 count slab (deg<=~40),
//     u16 csr (ids<65536, 4 indices per 8B load), fill bins 4->2.
//
// Pipeline:
//   A: t1b = bf16(rs_out .* (X @ W1))                      [GEMM]
//   B: agg=gather(t1b); h=relu(rs_in*agg+b1);
//      t2b = bf16(rs_out .* (h @ W2))                      [fused]
//   C: z = rs_in*gather(t2b)+b2 -> d_out; zb = bf16(z*rs_out)
//   D: recon = (rs_in .* gather(zb)) @ W3 + b3 -> d_out    [fused]

#define NN   50000     // nodes (fixed by problem)
#define HPB  128       // edge partitions
#define FNB  2         // fill node bins
#define FBIN 25000     // nodes per fill bin
typedef unsigned short u16;
typedef unsigned char  u8;

__device__ __forceinline__ float bfhi(unsigned u) {
    unsigned v = u & 0xFFFF0000u;
    return __builtin_bit_cast(float, v);
}
__device__ __forceinline__ float bflo(unsigned u) {
    unsigned v = u << 16;
    return __builtin_bit_cast(float, v);
}
__device__ __forceinline__ unsigned f2bf(float f) {   // f32 -> bf16 RNE
    unsigned u = __builtin_bit_cast(unsigned, f);
    return (u + 0x7FFFu + ((u >> 16) & 1u)) >> 16;
}

// ---------------- histogram: u8 slab[2][HPB][NN], packed-u8 LDS ----------------
// Per-node per-partition count <= degree (~40) << 255: u8 never overflows.
__global__ __launch_bounds__(256) void k_hist1(
    const int* __restrict__ src, const int* __restrict__ dst,
    u8* __restrict__ slab, int E, int slice)
{
    __shared__ unsigned h[NN / 4];               // 50KB, 4 u8 counters per word
    const int which = blockIdx.x / HPB;          // 0: src, 1: dst
    const int p     = blockIdx.x % HPB;
    const int* __restrict__ idx = which ? dst : src;

    for (int i = threadIdx.x; i < NN / 4; i += 256) h[i] = 0;
    __syncthreads();

    const int beg = p * slice;
    const int fin = min(beg + slice, E);
    for (int i = beg + threadIdx.x * 4; i + 3 < fin; i += 1024) {
        const int4 v = *(const int4*)(idx + i);
        atomicAdd(&h[v.x >> 2], 1u << ((v.x & 3) << 3));
        atomicAdd(&h[v.y >> 2], 1u << ((v.y & 3) << 3));
        atomicAdd(&h[v.z >> 2], 1u << ((v.z & 3) << 3));
        atomicAdd(&h[v.w >> 2], 1u << ((v.w & 3) << 3));
    }
    for (int i = beg + ((fin - beg) & ~3) + threadIdx.x; i < fin; i += 256) {
        const int u = idx[i];
        atomicAdd(&h[u >> 2], 1u << ((u & 3) << 3));
    }
    __syncthreads();

    unsigned* out = (unsigned*)(slab + (size_t)blockIdx.x * NN);  // NN%4==0
    for (int i = threadIdx.x; i < NN / 4; i += 256) out[i] = h[i];
}

// degrees -> rsqrt; dst half -> per-partition exclusive u8 offsets (in place);
// block-level inclusive scan of PADDED in-degree; csr dummy-init.
__global__ __launch_bounds__(256) void k_reduce_scan(
    u8* __restrict__ slab, float* __restrict__ rs_out, float* __restrict__ rs_in,
    int* __restrict__ partial, int* __restrict__ blocksum,
    unsigned* __restrict__ csr_words, int ncw, int N)
{
    __shared__ int tmp[256];
    const int tid = threadIdx.x;
    const int i = blockIdx.x * 256 + tid;

    int run = 0;
    if (i < N) {
        const u8* s_src = slab + i;
        u8*       s_dst = slab + (size_t)HPB * NN + i;
        int so = 0;
#pragma unroll 8
        for (int p = 0; p < HPB; ++p) so += s_src[(size_t)p * NN];
#pragma unroll 8
        for (int p = 0; p < HPB; ++p) {
            const int c = s_dst[(size_t)p * NN];
            s_dst[(size_t)p * NN] = (u8)run;
            run += c;
        }
        rs_out[i] = rsqrtf(fmaxf((float)so, 1.0f));
        rs_in[i]  = rsqrtf(fmaxf((float)run, 1.0f));
    }
    const int pad = (run + 15) & ~15;            // pad degree to mult of 16
    tmp[tid] = pad; __syncthreads();
    for (int off = 1; off < 256; off <<= 1) {
        int t = (tid >= off) ? tmp[tid - off] : 0;
        __syncthreads(); tmp[tid] += t; __syncthreads();
    }
    if (i < N) partial[i] = tmp[tid];
    if (tid == 255) blocksum[blockIdx.x] = tmp[255];

    // dummy-init padded csr: every slot = node id NN (the zero row)
    for (int w = blockIdx.x * 256 + tid; w < ncw; w += gridDim.x * 256)
        csr_words[w] = 0xC350C350u;              // 0xC350 == 50000 == NN
}

// Fused scan2+scan3: every block redundantly scans the (<=256) block sums.
__global__ __launch_bounds__(256) void k_scan23(
    const int* __restrict__ partial, const int* __restrict__ blocksum,
    int* __restrict__ row_start, int n, int nb)
{
    __shared__ int tmp[256];
    const int tid = threadIdx.x;
    int v = (tid < nb) ? blocksum[tid] : 0;
    tmp[tid] = v; __syncthreads();
    for (int off = 1; off < 256; off <<= 1) {
        int t = (tid >= off) ? tmp[tid - off] : 0;
        __syncthreads(); tmp[tid] += t; __syncthreads();
    }
    __syncthreads();
    const int i = blockIdx.x * 256 + tid;
    if (i < n) {
        const int base = (blockIdx.x > 0) ? tmp[blockIdx.x - 1] : 0;
        row_start[i + 1] = partial[i] + base;
        if (i == 0) row_start[0] = 0;
    }
}

// ---------- CSR fill: LDS cursors, u16 entries (zero global atomics) ----------
__global__ __launch_bounds__(256) void k_fill2(
    const int* __restrict__ src, const int* __restrict__ dst,
    const int* __restrict__ row_start, const u8* __restrict__ slab,
    u16* __restrict__ csr, int E, int slice, int N)
{
    __shared__ int cur[FBIN];                    // 100KB
    const int bin = blockIdx.x / HPB;
    const int p   = blockIdx.x % HPB;
    const int lo  = bin * FBIN;

    const u8* part_off = slab + (size_t)(HPB + p) * NN;   // dst half, partition p
    for (int j = threadIdx.x; j < FBIN; j += 256) {
        const int node = lo + j;
        cur[j] = row_start[node] + (int)part_off[node];
    }
    __syncthreads();

    const int beg = p * slice;
    const int fin = min(beg + slice, E);
    for (int i = beg + threadIdx.x * 4; i + 3 < fin; i += 1024) {
        const int4 d = *(const int4*)(dst + i);
        const int4 s = *(const int4*)(src + i);
        int u;
        u = d.x - lo; if ((unsigned)u < (unsigned)FBIN) csr[atomicAdd(&cur[u], 1)] = (u16)s.x;
        u = d.y - lo; if ((unsigned)u < (unsigned)FBIN) csr[atomicAdd(&cur[u], 1)] = (u16)s.y;
        u = d.z - lo; if ((unsigned)u < (unsigned)FBIN) csr[atomicAdd(&cur[u], 1)] = (u16)s.z;
        u = d.w - lo; if ((unsigned)u < (unsigned)FBIN) csr[atomicAdd(&cur[u], 1)] = (u16)s.w;
    }
    for (int i = beg + ((fin - beg) & ~3) + threadIdx.x; i < fin; i += 256) {
        int u = dst[i] - lo;
        if ((unsigned)u < (unsigned)FBIN) csr[atomicAdd(&cur[u], 1)] = (u16)src[i];
    }
}

// ---------------- GEMM A: t1b = bf16(rs_out .* (X @ W1)); zero dummy rows ----------------
template <int IN_F, int OUT_F, int TM>
__global__ __launch_bounds__(256) void k_gemm_bf16out(
    const float* __restrict__ X, const float* __restrict__ W,
    const float* __restrict__ rowscale, u16* __restrict__ Y,
    u16* __restrict__ t2b, u16* __restrict__ zb, int n)
{
    constexpr int CT  = OUT_F / 4;
    constexpr int RT  = 256 / CT;
    constexpr int RPT = TM / RT;
    constexpr int XS  = IN_F + 4;
    __shared__ float sW[IN_F * OUT_F];
    __shared__ float sX[TM * XS];
    const int tid = threadIdx.x;
    const int row0 = blockIdx.x * TM;

    if (blockIdx.x == 0) {                        // zero the dummy rows (id NN)
        if (tid < 32)      ((unsigned*)(Y   + (size_t)NN * 64))[tid]      = 0;
        else if (tid < 48) ((unsigned*)(t2b + (size_t)NN * 32))[tid - 32] = 0;
        else if (tid < 64) ((unsigned*)(zb  + (size_t)NN * 32))[tid - 48] = 0;
    }

    for (int i = tid; i < IN_F * OUT_F / 4; i += 256)
        ((float4*)sW)[i] = ((const float4*)W)[i];
    for (int i = tid; i < TM * IN_F / 4; i += 256) {
        const int r  = i / (IN_F / 4);
        const int c4 = (i % (IN_F / 4)) * 4;
        const int gr = row0 + r;
        float4 v = make_float4(0.f, 0.f, 0.f, 0.f);
        if (gr < n) v = *(const float4*)(X + (long)gr * IN_F + c4);
        *(float4*)(sX + r * XS + c4) = v;
    }
    __syncthreads();

    const int tc = tid % CT;
    const int tr = tid / CT;
    float4 acc[RPT];
#pragma unroll
    for (int i = 0; i < RPT; ++i) acc[i] = make_float4(0.f, 0.f, 0.f, 0.f);

#pragma unroll 8
    for (int k = 0; k < IN_F; ++k) {
        const float4 w = *(const float4*)(sW + k * OUT_F + 4 * tc);
#pragma unroll
        for (int i = 0; i < RPT; ++i) {
            const float xv = sX[(tr + i * RT) * XS + k];
            acc[i].x += xv * w.x; acc[i].y += xv * w.y;
            acc[i].z += xv * w.z; acc[i].w += xv * w.w;
        }
    }

#pragma unroll
    for (int i = 0; i < RPT; ++i) {
        const int gr = row0 + tr + i * RT;
        if (gr < n) {
            float4 v = acc[i];
            const float s = rowscale[gr];
            v.x *= s; v.y *= s; v.z *= s; v.w *= s;
            uint2 pk;
            pk.x = f2bf(v.x) | (f2bf(v.y) << 16);
            pk.y = f2bf(v.z) | (f2bf(v.w) << 16);
            *(uint2*)(Y + (size_t)gr * OUT_F + 4 * tc) = pk;
        }
    }
}

// accumulate one bf16x8 row chunk
#define ACC8(q) do { \
    a[0] += bflo((q).x); a[1] += bfhi((q).x); a[2] += bflo((q).y); a[3] += bfhi(q.y); \
    a[4] += bflo((q).z); a[5] += bfhi((q).z); a[6] += bflo((q).w); a[7] += bfhi(q.w); } while (0)

// gather 4 padded edges: 1 uint2 index load + 4 row loads
#define GATHER4(SRCB, RW) do { \
    const uint2 w = *(const uint2*)(csr + j); \
    const int s0 = w.x & 0xFFFF, s1 = w.x >> 16; \
    const int s2 = w.y & 0xFFFF, s3 = w.y >> 16; \
    const uint4 q0 = *(const uint4*)(SRCB + (size_t)s0 * RW + c8); \
    const uint4 q1 = *(const uint4*)(SRCB + (size_t)s1 * RW + c8); \
    const uint4 q2 = *(const uint4*)(SRCB + (size_t)s2 * RW + c8); \
    const uint4 q3 = *(const uint4*)(SRCB + (size_t)s3 * RW + c8); \
    ACC8(q0); ACC8(q1); ACC8(q2); ACC8(q3); } while (0)

// ---------------- fused B: gather(t1b,64) + relu + @W2 -> t2b ----------------
// 32 lanes/node = 8 col-lanes x 4 edge-quarters; combine via shfl_xor 8,16.
__global__ __launch_bounds__(256) void k_gather_gemm_B(
    const int* __restrict__ row_start, const u16* __restrict__ csr,
    const u16* __restrict__ t1b, const float* __restrict__ rs_in,
    const float* __restrict__ rs_out, const float* __restrict__ b1,
    const float* __restrict__ W2, u16* __restrict__ t2b, int N)
{
    __shared__ float sh[8][72];
    __shared__ float sW[64 * 32];
    const int tid = threadIdx.x;

    for (int i = tid; i < 64 * 32 / 4; i += 256)
        ((float4*)sW)[i] = ((const float4*)W2)[i];

    const int nloc = tid >> 5;           // 8 nodes/block
    const int sub  = tid & 31;
    const int qtr  = sub >> 3;
    const int c8   = (sub & 7) * 8;
    const int node = blockIdx.x * 8 + nloc;

    float a[8];
#pragma unroll
    for (int t = 0; t < 8; ++t) a[t] = 0.f;

    if (node < N) {
        const int beg  = row_start[node];
        const int qlen = (row_start[node + 1] - beg) >> 2;   // mult of 4
        const int j0 = beg + qtr * qlen;
        const int j1 = j0 + qlen;
        for (int j = j0; j < j1; j += 4) GATHER4(t1b, 64);
    }
#pragma unroll
    for (int t = 0; t < 8; ++t) {
        a[t] += __shfl_xor(a[t], 8);
        a[t] += __shfl_xor(a[t], 16);
    }

    if (node < N && qtr == 0) {
        const float rs = rs_in[node];
#pragma unroll
        for (int t = 0; t < 8; ++t)
            sh[nloc][c8 + t] = fmaxf(a[t] * rs + b1[c8 + t], 0.f);
    }
    __syncthreads();

    if (tid < 64) {                       // 8 nodes x 8 float4-cols
        const int n2 = tid >> 3;
        const int c4 = (tid & 7) * 4;
        float4 acc = make_float4(0.f, 0.f, 0.f, 0.f);
#pragma unroll 8
        for (int k = 0; k < 64; ++k) {
            const float xv = sh[n2][k];
            const float4 w = *(const float4*)(sW + k * 32 + c4);
            acc.x += xv * w.x; acc.y += xv * w.y; acc.z += xv * w.z; acc.w += xv * w.w;
        }
        const int gn = blockIdx.x * 8 + n2;
        if (gn < N) {
            const float s = rs_out[gn];
            uint2 pk;
            pk.x = f2bf(acc.x * s) | (f2bf(acc.y * s) << 16);
            pk.y = f2bf(acc.z * s) | (f2bf(acc.w * s) << 16);
            *(uint2*)(t2b + (size_t)gn * 32 + c4) = pk;
        }
    }
}

// ---------------- C: gather(t2b,32) -> z (f32, d_out) + zb shadow ----------------
// 16 lanes/node = 4 col-lanes x 4 edge-quarters; combine via shfl_xor 4,8.
__global__ __launch_bounds__(256) void k_gather_C(
    const int* __restrict__ row_start, const u16* __restrict__ csr,
    const u16* __restrict__ t2b, const float* __restrict__ rs_in,
    const float* __restrict__ rs_out, const float* __restrict__ b2,
    float* __restrict__ z, u16* __restrict__ zb, int N)
{
    const int node = blockIdx.x * 16 + (threadIdx.x >> 4);
    const int sub  = threadIdx.x & 15;
    const int qtr  = sub >> 2;
    const int c8   = (sub & 3) * 8;
    if (node >= N) return;               // 16-lane group exits together

    const int beg  = row_start[node];
    const int qlen = (row_start[node + 1] - beg) >> 2;
    const int j0 = beg + qtr * qlen;
    const int j1 = j0 + qlen;

    float a[8];
#pragma unroll
    for (int t = 0; t < 8; ++t) a[t] = 0.f;
    for (int j = j0; j < j1; j += 4) GATHER4(t2b, 32);

#pragma unroll
    for (int t = 0; t < 8; ++t) {
        a[t] += __shfl_xor(a[t], 4);
        a[t] += __shfl_xor(a[t], 8);
    }
    if (qtr) return;

    const float rs = rs_in[node];
    float v[8];
#pragma unroll
    for (int t = 0; t < 8; ++t) v[t] = a[t] * rs + b2[c8 + t];

    float* o = z + (size_t)node * 32 + c8;
    *(float4*)(o)     = make_float4(v[0], v[1], v[2], v[3]);
    *(float4*)(o + 4) = make_float4(v[4], v[5], v[6], v[7]);

    const float ss = rs_out[node];
    uint4 pk;
    pk.x = f2bf(v[0] * ss) | (f2bf(v[1] * ss) << 16);
    pk.y = f2bf(v[2] * ss) | (f2bf(v[3] * ss) << 16);
    pk.z = f2bf(v[4] * ss) | (f2bf(v[5] * ss) << 16);
    pk.w = f2bf(v[6] * ss) | (f2bf(v[7] * ss) << 16);
    *(uint4*)(zb + (size_t)node * 32 + c8) = pk;
}

// ---------------- fused D: gather(zb,32) + @W3 + b3 -> recon ----------------
// 16 lanes/node x 16 nodes/block; quarters combine via shfl_xor 4,8.
__global__ __launch_bounds__(256) void k_gather_gemm_D(
    const int* __restrict__ row_start, const u16* __restrict__ csr,
    const u16* __restrict__ zb, const float* __restrict__ rs_in,
    const float* __restrict__ W3, const float* __restrict__ b3,
    float* __restrict__ recon, int N)
{
    __shared__ float sa[16][36];
    __shared__ float sW[32 * 128];
    const int tid = threadIdx.x;

    for (int i = tid; i < 32 * 128 / 4; i += 256)
        ((float4*)sW)[i] = ((const float4*)W3)[i];

    const int nloc = tid >> 4;
    const int sub  = tid & 15;
    const int qtr  = sub >> 2;
    const int c8   = (sub & 3) * 8;
    const int node = blockIdx.x * 16 + nloc;

    float a[8];
#pragma unroll
    for (int t = 0; t < 8; ++t) a[t] = 0.f;

    if (node < N) {
        const int beg  = row_start[node];
        const int qlen = (row_start[node + 1] - beg) >> 2;
        const int j0 = beg + qtr * qlen;
        const int j1 = j0 + qlen;
        for (int j = j0; j < j1; j += 4) GATHER4(zb, 32);
    }
#pragma unroll
    for (int t = 0; t < 8; ++t) {
        a[t] += __shfl_xor(a[t], 4);
        a[t] += __shfl_xor(a[t], 8);
    }

    if (node < N && qtr == 0) {
        const float rs = rs_in[node];
#pragma unroll
        for (int t = 0; t < 8; ++t) sa[nloc][c8 + t] = a[t] * rs;
    }
    __syncthreads();

    // GEMM: 16 nodes x 128 cols; thread -> 2 nodes x 4 cols
    const int ng = (tid >> 5) * 2;
    const int c4 = (tid & 31) * 4;
    const float4 bb = *(const float4*)(b3 + c4);
    float4 acc[2];
    acc[0] = bb; acc[1] = bb;
#pragma unroll 4
    for (int k = 0; k < 32; ++k) {
        const float4 w = *(const float4*)(sW + k * 128 + c4);
#pragma unroll
        for (int i = 0; i < 2; ++i) {
            const float xv = sa[ng + i][k];
            acc[i].x += xv * w.x; acc[i].y += xv * w.y;
            acc[i].z += xv * w.z; acc[i].w += xv * w.w;
        }
    }
#pragma unroll
    for (int i = 0; i < 2; ++i) {
        const int gn = blockIdx.x * 16 + ng + i;
        if (gn < N) *(float4*)(recon + (size_t)gn * 128 + c4) = acc[i];
    }
}

extern "C" void kernel_launch(void* const* d_in, const int* in_sizes, int n_in,
                              void* d_out, int out_size, void* d_ws, size_t ws_size,
                              hipStream_t stream) {
    const float* feat = (const float*)d_in[0];   // [N,128]
    const int*   src  = (const int*)d_in[1];     // [E]
    const int*   dst  = (const int*)d_in[2];     // [E]
    const float* W1   = (const float*)d_in[3];   // [128,64]
    const float* b1   = (const float*)d_in[4];   // [64]
    const float* W2   = (const float*)d_in[5];   // [64,32]
    const float* b2   = (const float*)d_in[6];   // [32]
    const float* W3   = (const float*)d_in[7];   // [32,128]
    const float* b3   = (const float*)d_in[8];   // [128]

    const int E = in_sizes[1];
    const int N = in_sizes[0] / 128;             // 50000 == NN
    const int slice = (((E + HPB - 1) / HPB) + 3) & ~3;
    const int CSRMAX = E + 15 * N;               // padded-csr upper bound (entries)
    const int ncw = CSRMAX / 2;                  // u32 words

    // ---- workspace layout (16B alignment at every boundary) ----
    const size_t SLABB = 2UL * HPB * NN;          // u8 slab = 12.8MB
    u8*  slab     = (u8*)d_ws;                    // dead after k_fill2
    int* row_start= (int*)(slab + SLABB);         // [N+16] padded prefix
    int* scan_p   = row_start + N + 16;           // [N]
    int* blocksum = scan_p + N;                   // [256]
    u16* csr      = (u16*)(blocksum + 256);       // [CSRMAX] u16 node ids
    float* rs_out = (float*)(csr + CSRMAX);       // [N]
    float* rs_in  = rs_out + N;                   // [N]
    u16* t2b      = (u16*)(rs_in + N);            // [(N+8),32] bf16 (+dummy row N)
    u16* zb       = t2b + (size_t)(N + 8) * 32;   // [(N+8),32] bf16 (z * rs_out)
    u16* t1b      = (u16*)slab;                   // [(N+1),64] bf16, aliases slab

    float* z_out  = (float*)d_out;                // [N,32]
    float* recon  = z_out + (size_t)N * 32;       // [N,128]

    const int B = 256;
    const int nb_scan = (N + 255) / 256;          // 196

    // ---- atomic-free graph preprocessing (padded CSR, u8 counts, u16 ids) ----
    k_hist1<<<2 * HPB, B, 0, stream>>>(src, dst, slab, E, slice);
    k_reduce_scan<<<nb_scan, B, 0, stream>>>(slab, rs_out, rs_in, scan_p, blocksum,
                                             (unsigned*)csr, ncw, N);
    k_scan23<<<nb_scan, B, 0, stream>>>(scan_p, blocksum, row_start, N, nb_scan);
    k_fill2<<<FNB * HPB, B, 0, stream>>>(src, dst, row_start, slab, csr, E, slice, N);

    // ---- A: t1b = bf16(rs_out .* (X @ W1)); zero dummy rows ----
    k_gemm_bf16out<128, 64, 32><<<(N + 31) / 32, B, 0, stream>>>(
        feat, W1, rs_out, t1b, t2b, zb, N);

    // ---- B: gather(t1b) + relu + @W2 -> t2b ----
    k_gather_gemm_B<<<(N + 7) / 8, B, 0, stream>>>(
        row_start, csr, t1b, rs_in, rs_out, b1, W2, t2b, N);

    // ---- C: gather(t2b) -> z (d_out) + zb shadow ----
    k_gather_C<<<(N + 15) / 16, B, 0, stream>>>(
        row_start, csr, t2b, rs_in, rs_out, b2, z_out, zb, N);

    // ---- D: gather(zb) + @W3 + b3 -> recon ----
    k_gather_gemm_D<<<(N + 15) / 16, B, 0, stream>>>(
        row_start, csr, zb, rs_in, W3, b3, recon, N);
}

// Round 10
// 185.870 us; speedup vs baseline: 1.1722x; 1.0271x over previous
//
#include <hip/hip_runtime.h>
#include <hip/hip_bf16.h>

// GraphAutoencoder: 3x GraphConv (DGL norm='both') on fixed graph.
// N=50000 nodes, E=600000 edges, widths 128 -> 64 -> 32 -> 128.
//
// R1..R6: scatter->CSR gather, bf16 tables, row-local fusion: 485->213us.
// R7: degree-sort perm REGRESSED (locality). R8: 2-way edge split -> 202us.
// R9: pad-to-16 + 4-way edge split, u8 slab, u16 csr -> 191us.
//     (harness 0xAA poison of 256MiB ws = fixed ~44us in the timed window)
// R10: (a) MFMA (16x16x32 bf16) for GEMM-A: f32 VALU floor was ~10us alone;
//      (b) B/D: 32 nodes/block, batched gathers + full-256-thread GEMM,
//          cuts W2/W3 re-staging 4x/2x; (c) src-hist partitions 128->32
//          (out-degree only needs a sum; slab src half 6.4->1.6MB).
//
// Pipeline:
//   A: t1b = bf16(rs_out .* (X @ W1))                      [MFMA GEMM]
//   B: agg=gather(t1b); h=relu(rs_in*agg+b1);
//      t2b = bf16(rs_out .* (h @ W2))                      [fused]
//   C: z = rs_in*gather(t2b)+b2 -> d_out; zb = bf16(z*rs_out)
//   D: recon = (rs_in .* gather(zb)) @ W3 + b3 -> d_out    [fused]

#define NN   50000     // nodes (fixed by problem)
#define HPS  32        // src edge partitions (sum only)
#define HPD  128       // dst edge partitions (must match fill)
#define FNB  2         // fill node bins
#define FBIN 25000     // nodes per fill bin
typedef unsigned short u16;
typedef unsigned char  u8;
typedef __attribute__((ext_vector_type(8))) short bf16x8;
typedef __attribute__((ext_vector_type(4))) float f32x4;

__device__ __forceinline__ float bfhi(unsigned u) {
    unsigned v = u & 0xFFFF0000u;
    return __builtin_bit_cast(float, v);
}
__device__ __forceinline__ float bflo(unsigned u) {
    unsigned v = u << 16;
    return __builtin_bit_cast(float, v);
}
__device__ __forceinline__ unsigned f2bf(float f) {   // f32 -> bf16 RNE
    unsigned u = __builtin_bit_cast(unsigned, f);
    return (u + 0x7FFFu + ((u >> 16) & 1u)) >> 16;
}

// ---------------- histogram: u8 slab[HPS+HPD][NN], packed-u8 LDS ----------------
// Per-node per-partition count <= degree (~40) << 255: u8 never overflows.
__global__ __launch_bounds__(256) void k_hist1(
    const int* __restrict__ src, const int* __restrict__ dst,
    u8* __restrict__ slab, int E, int slice_s, int slice_d)
{
    __shared__ unsigned h[NN / 4];               // 50KB, 4 u8 counters per word
    const bool is_src = blockIdx.x < HPS;
    const int p       = is_src ? blockIdx.x : blockIdx.x - HPS;
    const int slice   = is_src ? slice_s : slice_d;
    const int* __restrict__ idx = is_src ? src : dst;

    for (int i = threadIdx.x; i < NN / 4; i += 256) h[i] = 0;
    __syncthreads();

    const int beg = p * slice;
    const int fin = min(beg + slice, E);
    for (int i = beg + threadIdx.x * 4; i + 3 < fin; i += 1024) {
        const int4 v = *(const int4*)(idx + i);
        atomicAdd(&h[v.x >> 2], 1u << ((v.x & 3) << 3));
        atomicAdd(&h[v.y >> 2], 1u << ((v.y & 3) << 3));
        atomicAdd(&h[v.z >> 2], 1u << ((v.z & 3) << 3));
        atomicAdd(&h[v.w >> 2], 1u << ((v.w & 3) << 3));
    }
    for (int i = beg + ((fin - beg) & ~3) + threadIdx.x; i < fin; i += 256) {
        const int u = idx[i];
        atomicAdd(&h[u >> 2], 1u << ((u & 3) << 3));
    }
    __syncthreads();

    unsigned* out = (unsigned*)(slab + (size_t)blockIdx.x * NN);  // NN%4==0
    for (int i = threadIdx.x; i < NN / 4; i += 256) out[i] = h[i];
}

// degrees -> rsqrt; dst half -> per-partition exclusive u8 offsets (in place);
// block-level inclusive scan of PADDED in-degree; csr dummy-init.
__global__ __launch_bounds__(256) void k_reduce_scan(
    u8* __restrict__ slab, float* __restrict__ rs_out, float* __restrict__ rs_in,
    int* __restrict__ partial, int* __restrict__ blocksum,
    unsigned* __restrict__ csr_words, int ncw, int N)
{
    __shared__ int tmp[256];
    const int tid = threadIdx.x;
    const int i = blockIdx.x * 256 + tid;

    int run = 0;
    if (i < N) {
        const u8* s_src = slab + i;
        u8*       s_dst = slab + (size_t)HPS * NN + i;
        int so = 0;
#pragma unroll 8
        for (int p = 0; p < HPS; ++p) so += s_src[(size_t)p * NN];
#pragma unroll 8
        for (int p = 0; p < HPD; ++p) {
            const int c = s_dst[(size_t)p * NN];
            s_dst[(size_t)p * NN] = (u8)run;
            run += c;
        }
        rs_out[i] = rsqrtf(fmaxf((float)so, 1.0f));
        rs_in[i]  = rsqrtf(fmaxf((float)run, 1.0f));
    }
    const int pad = (run + 15) & ~15;            // pad degree to mult of 16
    tmp[tid] = pad; __syncthreads();
    for (int off = 1; off < 256; off <<= 1) {
        int t = (tid >= off) ? tmp[tid - off] : 0;
        __syncthreads(); tmp[tid] += t; __syncthreads();
    }
    if (i < N) partial[i] = tmp[tid];
    if (tid == 255) blocksum[blockIdx.x] = tmp[255];

    // dummy-init padded csr: every slot = node id NN (the zero row)
    for (int w = blockIdx.x * 256 + tid; w < ncw; w += gridDim.x * 256)
        csr_words[w] = 0xC350C350u;              // 0xC350 == 50000 == NN
}

// Fused scan2+scan3: every block redundantly scans the (<=256) block sums.
__global__ __launch_bounds__(256) void k_scan23(
    const int* __restrict__ partial, const int* __restrict__ blocksum,
    int* __restrict__ row_start, int n, int nb)
{
    __shared__ int tmp[256];
    const int tid = threadIdx.x;
    int v = (tid < nb) ? blocksum[tid] : 0;
    tmp[tid] = v; __syncthreads();
    for (int off = 1; off < 256; off <<= 1) {
        int t = (tid >= off) ? tmp[tid - off] : 0;
        __syncthreads(); tmp[tid] += t; __syncthreads();
    }
    __syncthreads();
    const int i = blockIdx.x * 256 + tid;
    if (i < n) {
        const int base = (blockIdx.x > 0) ? tmp[blockIdx.x - 1] : 0;
        row_start[i + 1] = partial[i] + base;
        if (i == 0) row_start[0] = 0;
    }
}

// ---------- CSR fill: LDS cursors, u16 entries (zero global atomics) ----------
__global__ __launch_bounds__(256) void k_fill2(
    const int* __restrict__ src, const int* __restrict__ dst,
    const int* __restrict__ row_start, const u8* __restrict__ slab,
    u16* __restrict__ csr, int E, int slice, int N)
{
    __shared__ int cur[FBIN];                    // 100KB
    const int bin = blockIdx.x / HPD;
    const int p   = blockIdx.x % HPD;
    const int lo  = bin * FBIN;

    const u8* part_off = slab + (size_t)(HPS + p) * NN;   // dst half, partition p
    for (int j = threadIdx.x; j < FBIN; j += 256) {
        const int node = lo + j;
        cur[j] = row_start[node] + (int)part_off[node];
    }
    __syncthreads();

    const int beg = p * slice;
    const int fin = min(beg + slice, E);
    for (int i = beg + threadIdx.x * 4; i + 3 < fin; i += 1024) {
        const int4 d = *(const int4*)(dst + i);
        const int4 s = *(const int4*)(src + i);
        int u;
        u = d.x - lo; if ((unsigned)u < (unsigned)FBIN) csr[atomicAdd(&cur[u], 1)] = (u16)s.x;
        u = d.y - lo; if ((unsigned)u < (unsigned)FBIN) csr[atomicAdd(&cur[u], 1)] = (u16)s.y;
        u = d.z - lo; if ((unsigned)u < (unsigned)FBIN) csr[atomicAdd(&cur[u], 1)] = (u16)s.z;
        u = d.w - lo; if ((unsigned)u < (unsigned)FBIN) csr[atomicAdd(&cur[u], 1)] = (u16)s.w;
    }
    for (int i = beg + ((fin - beg) & ~3) + threadIdx.x; i < fin; i += 256) {
        int u = dst[i] - lo;
        if ((unsigned)u < (unsigned)FBIN) csr[atomicAdd(&cur[u], 1)] = (u16)src[i];
    }
}

// ---------------- MFMA GEMM A: t1b = bf16(rs_out .* (X @ W1)) ----------------
// Block: 64 rows x 64 cols; 4 waves, wave w -> 16-row m-slice, all 4 n-tiles.
// Layouts (HW-verified, guide §3): A-frag m=lane&15,k=quad*8+j;
// B-frag n=lane&15,k=quad*8+j (W1 staged transposed); C/D col=lane&15,row=quad*4+reg.
#define XS1 136    // padded bf16 row stride (odd 16B multiple -> conflict-free)
__global__ __launch_bounds__(256) void k_gemm_mfma_A(
    const float* __restrict__ X, const float* __restrict__ W1,
    const float* __restrict__ rs, u16* __restrict__ Y,
    u16* __restrict__ t2b, u16* __restrict__ zb, int N)
{
    __shared__ u16 sXb[64 * XS1];     // X rows, bf16
    __shared__ u16 sWt[64 * XS1];     // W1^T: [n][k], bf16
    const int tid = threadIdx.x;
    const int m0 = blockIdx.x * 64;

    if (blockIdx.x == 0) {            // zero dummy rows (id NN)
        if (tid < 32)      ((unsigned*)(Y   + (size_t)NN * 64))[tid]      = 0;
        else if (tid < 48) ((unsigned*)(t2b + (size_t)NN * 32))[tid - 32] = 0;
        else if (tid < 64) ((unsigned*)(zb  + (size_t)NN * 32))[tid - 48] = 0;
    }

    // stage W1^T as bf16 (one-time): read W1[k][n] coalesced, scatter to sWt[n][k]
    for (int i = tid; i < 128 * 64; i += 256) {
        const int k = i >> 6, n = i & 63;
        sWt[n * XS1 + k] = (u16)f2bf(W1[i]);
    }
    // stage X rows [m0, m0+64) as bf16 (packed uint2 writes)
    for (int i = tid; i < 64 * 32; i += 256) {       // 64 rows x 32 float4-chunks
        const int r  = i >> 5;
        const int c4 = (i & 31) * 4;
        const int gr = m0 + r;
        float4 v = make_float4(0.f, 0.f, 0.f, 0.f);
        if (gr < N) v = *(const float4*)(X + (size_t)gr * 128 + c4);
        uint2 pk;
        pk.x = f2bf(v.x) | (f2bf(v.y) << 16);
        pk.y = f2bf(v.z) | (f2bf(v.w) << 16);
        *(uint2*)(sXb + r * XS1 + c4) = pk;
    }
    __syncthreads();

    const int wv   = tid >> 6;
    const int lane = tid & 63;
    const int l15  = lane & 15;
    const int quad = lane >> 4;

    f32x4 acc[4] = {};
    const u16* ax = sXb + (wv * 16 + l15) * XS1 + quad * 8;
    const u16* bx = sWt + l15 * XS1 + quad * 8;
#pragma unroll
    for (int ks = 0; ks < 4; ++ks) {
        const bf16x8 af = *(const bf16x8*)(ax + ks * 32);
#pragma unroll
        for (int nt = 0; nt < 4; ++nt) {
            const bf16x8 bf = *(const bf16x8*)(bx + nt * 16 * XS1 + ks * 32);
            acc[nt] = __builtin_amdgcn_mfma_f32_16x16x32_bf16(af, bf, acc[nt], 0, 0, 0);
        }
    }

    const int mrow = m0 + wv * 16 + quad * 4;
    float sc[4];
#pragma unroll
    for (int r = 0; r < 4; ++r) sc[r] = (mrow + r < N) ? rs[mrow + r] : 0.f;
#pragma unroll
    for (int r = 0; r < 4; ++r) {
        const int gr = mrow + r;
        if (gr < N) {
#pragma unroll
            for (int nt = 0; nt < 4; ++nt)
                Y[(size_t)gr * 64 + nt * 16 + l15] = (u16)f2bf(acc[nt][r] * sc[r]);
        }
    }
}

// accumulate one bf16x8 row chunk
#define ACC8(q) do { \
    a[0] += bflo((q).x); a[1] += bfhi((q).x); a[2] += bflo((q).y); a[3] += bfhi((q).y); \
    a[4] += bflo((q).z); a[5] += bfhi((q).z); a[6] += bflo((q).w); a[7] += bfhi((q).w); } while (0)

// gather 4 padded edges: 1 uint2 index load + 4 row loads
#define GATHER4(SRCB, RW) do { \
    const uint2 w = *(const uint2*)(csr + j); \
    const int s0 = w.x & 0xFFFF, s1 = w.x >> 16; \
    const int s2 = w.y & 0xFFFF, s3 = w.y >> 16; \
    const uint4 q0 = *(const uint4*)(SRCB + (size_t)s0 * RW + c8); \
    const uint4 q1 = *(const uint4*)(SRCB + (size_t)s1 * RW + c8); \
    const uint4 q2 = *(const uint4*)(SRCB + (size_t)s2 * RW + c8); \
    const uint4 q3 = *(const uint4*)(SRCB + (size_t)s3 * RW + c8); \
    ACC8(q0); ACC8(q1); ACC8(q2); ACC8(q3); } while (0)

// ---------------- fused B: gather(t1b,64) + relu + @W2 -> t2b ----------------
// 32 nodes/block: 4 gather batches (8 nodes x 32 lanes), then 256-thread GEMM.
__global__ __launch_bounds__(256) void k_gather_gemm_B(
    const int* __restrict__ row_start, const u16* __restrict__ csr,
    const u16* __restrict__ t1b, const float* __restrict__ rs_in,
    const float* __restrict__ rs_out, const float* __restrict__ b1,
    const float* __restrict__ W2, u16* __restrict__ t2b, int N)
{
    __shared__ float sh[32][72];
    __shared__ float sW[64 * 32];
    const int tid = threadIdx.x;

    for (int i = tid; i < 64 * 32 / 4; i += 256)
        ((float4*)sW)[i] = ((const float4*)W2)[i];

    const int nb   = tid >> 5;           // 8 node-groups in flight
    const int sub  = tid & 31;
    const int qtr  = sub >> 3;
    const int c8   = (sub & 7) * 8;

#pragma unroll
    for (int b = 0; b < 4; ++b) {
        const int nloc = b * 8 + nb;
        const int node = blockIdx.x * 32 + nloc;
        float a[8];
#pragma unroll
        for (int t = 0; t < 8; ++t) a[t] = 0.f;
        if (node < N) {
            const int beg  = row_start[node];
            const int qlen = (row_start[node + 1] - beg) >> 2;
            const int j0 = beg + qtr * qlen;
            const int j1 = j0 + qlen;
            for (int j = j0; j < j1; j += 4) GATHER4(t1b, 64);
        }
#pragma unroll
        for (int t = 0; t < 8; ++t) {
            a[t] += __shfl_xor(a[t], 8);
            a[t] += __shfl_xor(a[t], 16);
        }
        if (node < N && qtr == 0) {
            const float rs = rs_in[node];
#pragma unroll
            for (int t = 0; t < 8; ++t)
                sh[nloc][c8 + t] = fmaxf(a[t] * rs + b1[c8 + t], 0.f);
        }
    }
    __syncthreads();

    // GEMM: 32 nodes x 32 cols; all 256 threads (node=tid/8, 4 cols each)
    const int n2 = tid >> 3;
    const int c4 = (tid & 7) * 4;
    float4 acc = make_float4(0.f, 0.f, 0.f, 0.f);
#pragma unroll 8
    for (int k = 0; k < 64; ++k) {
        const float xv = sh[n2][k];
        const float4 w = *(const float4*)(sW + k * 32 + c4);
        acc.x += xv * w.x; acc.y += xv * w.y; acc.z += xv * w.z; acc.w += xv * w.w;
    }
    const int gn = blockIdx.x * 32 + n2;
    if (gn < N) {
        const float s = rs_out[gn];
        uint2 pk;
        pk.x = f2bf(acc.x * s) | (f2bf(acc.y * s) << 16);
        pk.y = f2bf(acc.z * s) | (f2bf(acc.w * s) << 16);
        *(uint2*)(t2b + (size_t)gn * 32 + c4) = pk;
    }
}

// ---------------- C: gather(t2b,32) -> z (f32, d_out) + zb shadow ----------------
// 16 lanes/node = 4 col-lanes x 4 edge-quarters; combine via shfl_xor 4,8.
__global__ __launch_bounds__(256) void k_gather_C(
    const int* __restrict__ row_start, const u16* __restrict__ csr,
    const u16* __restrict__ t2b, const float* __restrict__ rs_in,
    const float* __restrict__ rs_out, const float* __restrict__ b2,
    float* __restrict__ z, u16* __restrict__ zb, int N)
{
    const int node = blockIdx.x * 16 + (threadIdx.x >> 4);
    const int sub  = threadIdx.x & 15;
    const int qtr  = sub >> 2;
    const int c8   = (sub & 3) * 8;
    if (node >= N) return;               // 16-lane group exits together

    const int beg  = row_start[node];
    const int qlen = (row_start[node + 1] - beg) >> 2;
    const int j0 = beg + qtr * qlen;
    const int j1 = j0 + qlen;

    float a[8];
#pragma unroll
    for (int t = 0; t < 8; ++t) a[t] = 0.f;
    for (int j = j0; j < j1; j += 4) GATHER4(t2b, 32);

#pragma unroll
    for (int t = 0; t < 8; ++t) {
        a[t] += __shfl_xor(a[t], 4);
        a[t] += __shfl_xor(a[t], 8);
    }
    if (qtr) return;

    const float rs = rs_in[node];
    float v[8];
#pragma unroll
    for (int t = 0; t < 8; ++t) v[t] = a[t] * rs + b2[c8 + t];

    float* o = z + (size_t)node * 32 + c8;
    *(float4*)(o)     = make_float4(v[0], v[1], v[2], v[3]);
    *(float4*)(o + 4) = make_float4(v[4], v[5], v[6], v[7]);

    const float ss = rs_out[node];
    uint4 pk;
    pk.x = f2bf(v[0] * ss) | (f2bf(v[1] * ss) << 16);
    pk.y = f2bf(v[2] * ss) | (f2bf(v[3] * ss) << 16);
    pk.z = f2bf(v[4] * ss) | (f2bf(v[5] * ss) << 16);
    pk.w = f2bf(v[6] * ss) | (f2bf(v[7] * ss) << 16);
    *(uint4*)(zb + (size_t)node * 32 + c8) = pk;
}

// ---------------- fused D: gather(zb,32) + @W3 + b3 -> recon ----------------
// 32 nodes/block: 2 gather batches (16 nodes x 16 lanes), then 256-thread GEMM.
__global__ __launch_bounds__(256) void k_gather_gemm_D(
    const int* __restrict__ row_start, const u16* __restrict__ csr,
    const u16* __restrict__ zb, const float* __restrict__ rs_in,
    const float* __restrict__ W3, const float* __restrict__ b3,
    float* __restrict__ recon, int N)
{
    __shared__ float sa[32][36];
    __shared__ float sW[32 * 128];
    const int tid = threadIdx.x;

    for (int i = tid; i < 32 * 128 / 4; i += 256)
        ((float4*)sW)[i] = ((const float4*)W3)[i];

    const int nb   = tid >> 4;           // 16 node-groups in flight
    const int sub  = tid & 15;
    const int qtr  = sub >> 2;
    const int c8   = (sub & 3) * 8;

#pragma unroll
    for (int b = 0; b < 2; ++b) {
        const int nloc = b * 16 + nb;
        const int node = blockIdx.x * 32 + nloc;
        float a[8];
#pragma unroll
        for (int t = 0; t < 8; ++t) a[t] = 0.f;
        if (node < N) {
            const int beg  = row_start[node];
            const int qlen = (row_start[node + 1] - beg) >> 2;
            const int j0 = beg + qtr * qlen;
            const int j1 = j0 + qlen;
            for (int j = j0; j < j1; j += 4) GATHER4(zb, 32);
        }
#pragma unroll
        for (int t = 0; t < 8; ++t) {
            a[t] += __shfl_xor(a[t], 4);
            a[t] += __shfl_xor(a[t], 8);
        }
        if (node < N && qtr == 0) {
            const float rs = rs_in[node];
#pragma unroll
            for (int t = 0; t < 8; ++t) sa[nloc][c8 + t] = a[t] * rs;
        }
    }
    __syncthreads();

    // GEMM: 32 nodes x 128 cols; thread -> 4 nodes x 4 cols
    const int ng = (tid >> 5) * 4;
    const int c4 = (tid & 31) * 4;
    const float4 bb = *(const float4*)(b3 + c4);
    float4 acc[4];
#pragma unroll
    for (int i = 0; i < 4; ++i) acc[i] = bb;
#pragma unroll 4
    for (int k = 0; k < 32; ++k) {
        const float4 w = *(const float4*)(sW + k * 128 + c4);
#pragma unroll
        for (int i = 0; i < 4; ++i) {
            const float xv = sa[ng + i][k];
            acc[i].x += xv * w.x; acc[i].y += xv * w.y;
            acc[i].z += xv * w.z; acc[i].w += xv * w.w;
        }
    }
#pragma unroll
    for (int i = 0; i < 4; ++i) {
        const int gn = blockIdx.x * 32 + ng + i;
        if (gn < N) *(float4*)(recon + (size_t)gn * 128 + c4) = acc[i];
    }
}

extern "C" void kernel_launch(void* const* d_in, const int* in_sizes, int n_in,
                              void* d_out, int out_size, void* d_ws, size_t ws_size,
                              hipStream_t stream) {
    const float* feat = (const float*)d_in[0];   // [N,128]
    const int*   src  = (const int*)d_in[1];     // [E]
    const int*   dst  = (const int*)d_in[2];     // [E]
    const float* W1   = (const float*)d_in[3];   // [128,64]
    const float* b1   = (const float*)d_in[4];   // [64]
    const float* W2   = (const float*)d_in[5];   // [64,32]
    const float* b2   = (const float*)d_in[6];   // [32]
    const float* W3   = (const float*)d_in[7];   // [32,128]
    const float* b3   = (const float*)d_in[8];   // [128]

    const int E = in_sizes[1];
    const int N = in_sizes[0] / 128;             // 50000 == NN
    const int slice_s = (((E + HPS - 1) / HPS) + 3) & ~3;
    const int slice_d = (((E + HPD - 1) / HPD) + 3) & ~3;
    const int CSRMAX = E + 15 * N;               // padded-csr upper bound (entries)
    const int ncw = CSRMAX / 2;                  // u32 words

    // ---- workspace layout (16B alignment at every boundary) ----
    const size_t SLABB = (size_t)(HPS + HPD) * NN;  // u8 slab = 8MB
    u8*  slab     = (u8*)d_ws;                    // dead after k_fill2
    int* row_start= (int*)(slab + SLABB);         // [N+16] padded prefix
    int* scan_p   = row_start + N + 16;           // [N]
    int* blocksum = scan_p + N;                   // [256]
    u16* csr      = (u16*)(blocksum + 256);       // [CSRMAX] u16 node ids
    float* rs_out = (float*)(csr + CSRMAX);       // [N]
    float* rs_in  = rs_out + N;                   // [N]
    u16* t2b      = (u16*)(rs_in + N);            // [(N+8),32] bf16 (+dummy row N)
    u16* zb       = t2b + (size_t)(N + 8) * 32;   // [(N+8),32] bf16 (z * rs_out)
    u16* t1b      = (u16*)slab;                   // [(N+1),64] bf16 = 6.4MB <= slab

    float* z_out  = (float*)d_out;                // [N,32]
    float* recon  = z_out + (size_t)N * 32;       // [N,128]

    const int B = 256;
    const int nb_scan = (N + 255) / 256;          // 196

    // ---- atomic-free graph preprocessing (padded CSR, u8 counts, u16 ids) ----
    k_hist1<<<HPS + HPD, B, 0, stream>>>(src, dst, slab, E, slice_s, slice_d);
    k_reduce_scan<<<nb_scan, B, 0, stream>>>(slab, rs_out, rs_in, scan_p, blocksum,
                                             (unsigned*)csr, ncw, N);
    k_scan23<<<nb_scan, B, 0, stream>>>(scan_p, blocksum, row_start, N, nb_scan);
    k_fill2<<<FNB * HPD, B, 0, stream>>>(src, dst, row_start, slab, csr, E, slice_d, N);

    // ---- A: t1b = bf16(rs_out .* (X @ W1)) via MFMA; zero dummy rows ----
    k_gemm_mfma_A<<<(N + 63) / 64, B, 0, stream>>>(
        feat, W1, rs_out, t1b, t2b, zb, N);

    // ---- B: gather(t1b) + relu + @W2 -> t2b ----
    k_gather_gemm_B<<<(N + 31) / 32, B, 0, stream>>>(
        row_start, csr, t1b, rs_in, rs_out, b1, W2, t2b, N);

    // ---- C: gather(t2b) -> z (d_out) + zb shadow ----
    k_gather_C<<<(N + 15) / 16, B, 0, stream>>>(
        row_start, csr, t2b, rs_in, rs_out, b2, z_out, zb, N);

    // ---- D: gather(zb) + @W3 + b3 -> recon ----
    k_gather_gemm_D<<<(N + 31) / 32, B, 0, stream>>>(
        row_start, csr, zb, rs_in, W3, b3, recon, N);
}

// Round 11
// 183.238 us; speedup vs baseline: 1.1890x; 1.0144x over previous
//
#include <hip/hip_runtime.h>
#include <hip/hip_bf16.h>

// GraphAutoencoder: 3x GraphConv (DGL norm='both') on fixed graph.
// N=50000 nodes, E=600000 edges, widths 128 -> 64 -> 32 -> 128.
//
// R1..R6: scatter->CSR gather, bf16 tables, row-local fusion: 485->213us.
// R7: degree-sort perm REGRESSED (locality). R8: 2-way edge split -> 202us.
// R9: pad-to-16 + 4-way edge split, u8 slab, u16 csr -> 191us.
// R10: MFMA GEMM-A, 32-node B/D blocks, src-hist 32 partitions -> 186us.
//     (harness 0xAA poison of 256MiB ws = fixed ~44us in the timed window)
// R11: seg[node]=(start,qlen) uint2 -> one aligned 8B load replaces two 4B
//      row_start loads at the head of every gather chain; B/D preload all
//      batches' seg up front (independent loads in flight).
//
// Pipeline:
//   A: t1b = bf16(rs_out .* (X @ W1))                      [MFMA GEMM]
//   B: agg=gather(t1b); h=relu(rs_in*agg+b1);
//      t2b = bf16(rs_out .* (h @ W2))                      [fused]
//   C: z = rs_in*gather(t2b)+b2 -> d_out; zb = bf16(z*rs_out)
//   D: recon = (rs_in .* gather(zb)) @ W3 + b3 -> d_out    [fused]

#define NN   50000     // nodes (fixed by problem)
#define HPS  32        // src edge partitions (sum only)
#define HPD  128       // dst edge partitions (must match fill)
#define FNB  2         // fill node bins
#define FBIN 25000     // nodes per fill bin
typedef unsigned short u16;
typedef unsigned char  u8;
typedef __attribute__((ext_vector_type(8))) short bf16x8;
typedef __attribute__((ext_vector_type(4))) float f32x4;

__device__ __forceinline__ float bfhi(unsigned u) {
    unsigned v = u & 0xFFFF0000u;
    return __builtin_bit_cast(float, v);
}
__device__ __forceinline__ float bflo(unsigned u) {
    unsigned v = u << 16;
    return __builtin_bit_cast(float, v);
}
__device__ __forceinline__ unsigned f2bf(float f) {   // f32 -> bf16 RNE
    unsigned u = __builtin_bit_cast(unsigned, f);
    return (u + 0x7FFFu + ((u >> 16) & 1u)) >> 16;
}

// ---------------- histogram: u8 slab[HPS+HPD][NN], packed-u8 LDS ----------------
__global__ __launch_bounds__(256) void k_hist1(
    const int* __restrict__ src, const int* __restrict__ dst,
    u8* __restrict__ slab, int E, int slice_s, int slice_d)
{
    __shared__ unsigned h[NN / 4];               // 50KB, 4 u8 counters per word
    const bool is_src = blockIdx.x < HPS;
    const int p       = is_src ? blockIdx.x : blockIdx.x - HPS;
    const int slice   = is_src ? slice_s : slice_d;
    const int* __restrict__ idx = is_src ? src : dst;

    for (int i = threadIdx.x; i < NN / 4; i += 256) h[i] = 0;
    __syncthreads();

    const int beg = p * slice;
    const int fin = min(beg + slice, E);
    for (int i = beg + threadIdx.x * 4; i + 3 < fin; i += 1024) {
        const int4 v = *(const int4*)(idx + i);
        atomicAdd(&h[v.x >> 2], 1u << ((v.x & 3) << 3));
        atomicAdd(&h[v.y >> 2], 1u << ((v.y & 3) << 3));
        atomicAdd(&h[v.z >> 2], 1u << ((v.z & 3) << 3));
        atomicAdd(&h[v.w >> 2], 1u << ((v.w & 3) << 3));
    }
    for (int i = beg + ((fin - beg) & ~3) + threadIdx.x; i < fin; i += 256) {
        const int u = idx[i];
        atomicAdd(&h[u >> 2], 1u << ((u & 3) << 3));
    }
    __syncthreads();

    unsigned* out = (unsigned*)(slab + (size_t)blockIdx.x * NN);  // NN%4==0
    for (int i = threadIdx.x; i < NN / 4; i += 256) out[i] = h[i];
}

// degrees -> rsqrt; dst half -> per-partition exclusive u8 offsets (in place);
// block-level inclusive scan of PADDED in-degree; pad4 export; csr dummy-init.
__global__ __launch_bounds__(256) void k_reduce_scan(
    u8* __restrict__ slab, float* __restrict__ rs_out, float* __restrict__ rs_in,
    int* __restrict__ partial, int* __restrict__ blocksum, u8* __restrict__ pad4,
    unsigned* __restrict__ csr_words, int ncw, int N)
{
    __shared__ int tmp[256];
    const int tid = threadIdx.x;
    const int i = blockIdx.x * 256 + tid;

    int run = 0;
    if (i < N) {
        const u8* s_src = slab + i;
        u8*       s_dst = slab + (size_t)HPS * NN + i;
        int so = 0;
#pragma unroll 8
        for (int p = 0; p < HPS; ++p) so += s_src[(size_t)p * NN];
#pragma unroll 8
        for (int p = 0; p < HPD; ++p) {
            const int c = s_dst[(size_t)p * NN];
            s_dst[(size_t)p * NN] = (u8)run;
            run += c;
        }
        rs_out[i] = rsqrtf(fmaxf((float)so, 1.0f));
        rs_in[i]  = rsqrtf(fmaxf((float)run, 1.0f));
    }
    const int pad = (run + 15) & ~15;            // pad degree to mult of 16
    if (i < N) pad4[i] = (u8)(pad >> 2);         // quarter length in entries
    tmp[tid] = pad; __syncthreads();
    for (int off = 1; off < 256; off <<= 1) {
        int t = (tid >= off) ? tmp[tid - off] : 0;
        __syncthreads(); tmp[tid] += t; __syncthreads();
    }
    if (i < N) partial[i] = tmp[tid];
    if (tid == 255) blocksum[blockIdx.x] = tmp[255];

    // dummy-init padded csr: every slot = node id NN (the zero row)
    for (int w = blockIdx.x * 256 + tid; w < ncw; w += gridDim.x * 256)
        csr_words[w] = 0xC350C350u;              // 0xC350 == 50000 == NN
}

// Fused scan2+scan3 -> seg[node] = (start, quarter_len_entries) uint2.
__global__ __launch_bounds__(256) void k_scan23(
    const int* __restrict__ partial, const int* __restrict__ blocksum,
    const u8* __restrict__ pad4, uint2* __restrict__ seg, int n, int nb)
{
    __shared__ int tmp[256];
    const int tid = threadIdx.x;
    int v = (tid < nb) ? blocksum[tid] : 0;
    tmp[tid] = v; __syncthreads();
    for (int off = 1; off < 256; off <<= 1) {
        int t = (tid >= off) ? tmp[tid - off] : 0;
        __syncthreads(); tmp[tid] += t; __syncthreads();
    }
    __syncthreads();
    const int i = blockIdx.x * 256 + tid;
    if (i < n) {
        const int base = (blockIdx.x > 0) ? tmp[blockIdx.x - 1] : 0;
        const int incl = partial[i] + base;
        const unsigned q = pad4[i];
        seg[i] = make_uint2((unsigned)(incl - (int)(q << 2)), q);
    }
}

// ---------- CSR fill: LDS cursors, u16 entries (zero global atomics) ----------
__global__ __launch_bounds__(256) void k_fill2(
    const int* __restrict__ src, const int* __restrict__ dst,
    const uint2* __restrict__ seg, const u8* __restrict__ slab,
    u16* __restrict__ csr, int E, int slice, int N)
{
    __shared__ int cur[FBIN];                    // 100KB
    const int bin = blockIdx.x / HPD;
    const int p   = blockIdx.x % HPD;
    const int lo  = bin * FBIN;

    const u8* part_off = slab + (size_t)(HPS + p) * NN;   // dst half, partition p
    for (int j = threadIdx.x; j < FBIN; j += 256) {
        const int node = lo + j;
        cur[j] = (int)seg[node].x + (int)part_off[node];
    }
    __syncthreads();

    const int beg = p * slice;
    const int fin = min(beg + slice, E);
    for (int i = beg + threadIdx.x * 4; i + 3 < fin; i += 1024) {
        const int4 d = *(const int4*)(dst + i);
        const int4 s = *(const int4*)(src + i);
        int u;
        u = d.x - lo; if ((unsigned)u < (unsigned)FBIN) csr[atomicAdd(&cur[u], 1)] = (u16)s.x;
        u = d.y - lo; if ((unsigned)u < (unsigned)FBIN) csr[atomicAdd(&cur[u], 1)] = (u16)s.y;
        u = d.z - lo; if ((unsigned)u < (unsigned)FBIN) csr[atomicAdd(&cur[u], 1)] = (u16)s.z;
        u = d.w - lo; if ((unsigned)u < (unsigned)FBIN) csr[atomicAdd(&cur[u], 1)] = (u16)s.w;
    }
    for (int i = beg + ((fin - beg) & ~3) + threadIdx.x; i < fin; i += 256) {
        int u = dst[i] - lo;
        if ((unsigned)u < (unsigned)FBIN) csr[atomicAdd(&cur[u], 1)] = (u16)src[i];
    }
}

// ---------------- MFMA GEMM A: t1b = bf16(rs_out .* (X @ W1)) ----------------
#define XS1 136    // padded bf16 row stride
__global__ __launch_bounds__(256) void k_gemm_mfma_A(
    const float* __restrict__ X, const float* __restrict__ W1,
    const float* __restrict__ rs, u16* __restrict__ Y,
    u16* __restrict__ t2b, u16* __restrict__ zb, int N)
{
    __shared__ u16 sXb[64 * XS1];     // X rows, bf16
    __shared__ u16 sWt[64 * XS1];     // W1^T: [n][k], bf16
    const int tid = threadIdx.x;
    const int m0 = blockIdx.x * 64;

    if (blockIdx.x == 0) {            // zero dummy rows (id NN)
        if (tid < 32)      ((unsigned*)(Y   + (size_t)NN * 64))[tid]      = 0;
        else if (tid < 48) ((unsigned*)(t2b + (size_t)NN * 32))[tid - 32] = 0;
        else if (tid < 64) ((unsigned*)(zb  + (size_t)NN * 32))[tid - 48] = 0;
    }

    for (int i = tid; i < 128 * 64; i += 256) {
        const int k = i >> 6, n = i & 63;
        sWt[n * XS1 + k] = (u16)f2bf(W1[i]);
    }
    for (int i = tid; i < 64 * 32; i += 256) {       // 64 rows x 32 float4-chunks
        const int r  = i >> 5;
        const int c4 = (i & 31) * 4;
        const int gr = m0 + r;
        float4 v = make_float4(0.f, 0.f, 0.f, 0.f);
        if (gr < N) v = *(const float4*)(X + (size_t)gr * 128 + c4);
        uint2 pk;
        pk.x = f2bf(v.x) | (f2bf(v.y) << 16);
        pk.y = f2bf(v.z) | (f2bf(v.w) << 16);
        *(uint2*)(sXb + r * XS1 + c4) = pk;
    }
    __syncthreads();

    const int wv   = tid >> 6;
    const int lane = tid & 63;
    const int l15  = lane & 15;
    const int quad = lane >> 4;

    f32x4 acc[4] = {};
    const u16* ax = sXb + (wv * 16 + l15) * XS1 + quad * 8;
    const u16* bx = sWt + l15 * XS1 + quad * 8;
#pragma unroll
    for (int ks = 0; ks < 4; ++ks) {
        const bf16x8 af = *(const bf16x8*)(ax + ks * 32);
#pragma unroll
        for (int nt = 0; nt < 4; ++nt) {
            const bf16x8 bf = *(const bf16x8*)(bx + nt * 16 * XS1 + ks * 32);
            acc[nt] = __builtin_amdgcn_mfma_f32_16x16x32_bf16(af, bf, acc[nt], 0, 0, 0);
        }
    }

    const int mrow = m0 + wv * 16 + quad * 4;
    float sc[4];
#pragma unroll
    for (int r = 0; r < 4; ++r) sc[r] = (mrow + r < N) ? rs[mrow + r] : 0.f;
#pragma unroll
    for (int r = 0; r < 4; ++r) {
        const int gr = mrow + r;
        if (gr < N) {
#pragma unroll
            for (int nt = 0; nt < 4; ++nt)
                Y[(size_t)gr * 64 + nt * 16 + l15] = (u16)f2bf(acc[nt][r] * sc[r]);
        }
    }
}

// accumulate one bf16x8 row chunk
#define ACC8(q) do { \
    a[0] += bflo((q).x); a[1] += bfhi((q).x); a[2] += bflo((q).y); a[3] += bfhi((q).y); \
    a[4] += bflo((q).z); a[5] += bfhi((q).z); a[6] += bflo((q).w); a[7] += bfhi((q).w); } while (0)

// gather 4 padded edges: 1 uint2 index load + 4 row loads
#define GATHER4(SRCB, RW) do { \
    const uint2 w = *(const uint2*)(csr + j); \
    const int s0 = w.x & 0xFFFF, s1 = w.x >> 16; \
    const int s2 = w.y & 0xFFFF, s3 = w.y >> 16; \
    const uint4 q0 = *(const uint4*)(SRCB + (size_t)s0 * RW + c8); \
    const uint4 q1 = *(const uint4*)(SRCB + (size_t)s1 * RW + c8); \
    const uint4 q2 = *(const uint4*)(SRCB + (size_t)s2 * RW + c8); \
    const uint4 q3 = *(const uint4*)(SRCB + (size_t)s3 * RW + c8); \
    ACC8(q0); ACC8(q1); ACC8(q2); ACC8(q3); } while (0)

// ---------------- fused B: gather(t1b,64) + relu + @W2 -> t2b ----------------
// 32 nodes/block: 4 gather batches (8 nodes x 32 lanes), then 256-thread GEMM.
__global__ __launch_bounds__(256) void k_gather_gemm_B(
    const uint2* __restrict__ seg, const u16* __restrict__ csr,
    const u16* __restrict__ t1b, const float* __restrict__ rs_in,
    const float* __restrict__ rs_out, const float* __restrict__ b1,
    const float* __restrict__ W2, u16* __restrict__ t2b, int N)
{
    __shared__ float sh[32][72];
    __shared__ float sW[64 * 32];
    const int tid = threadIdx.x;

    for (int i = tid; i < 64 * 32 / 4; i += 256)
        ((float4*)sW)[i] = ((const float4*)W2)[i];

    const int nb   = tid >> 5;           // 8 node-groups in flight
    const int sub  = tid & 31;
    const int qtr  = sub >> 3;
    const int c8   = (sub & 7) * 8;

    uint2 sgs[4];                        // preload all batches' segments
#pragma unroll
    for (int b = 0; b < 4; ++b) {
        const int node = blockIdx.x * 32 + b * 8 + nb;
        sgs[b] = (node < N) ? seg[node] : make_uint2(0u, 0u);
    }

#pragma unroll
    for (int b = 0; b < 4; ++b) {
        const int nloc = b * 8 + nb;
        const int node = blockIdx.x * 32 + nloc;
        float a[8];
#pragma unroll
        for (int t = 0; t < 8; ++t) a[t] = 0.f;
        const int j0 = (int)sgs[b].x + qtr * (int)sgs[b].y;
        const int j1 = j0 + (int)sgs[b].y;
        for (int j = j0; j < j1; j += 4) GATHER4(t1b, 64);
#pragma unroll
        for (int t = 0; t < 8; ++t) {
            a[t] += __shfl_xor(a[t], 8);
            a[t] += __shfl_xor(a[t], 16);
        }
        if (node < N && qtr == 0) {
            const float rs = rs_in[node];
#pragma unroll
            for (int t = 0; t < 8; ++t)
                sh[nloc][c8 + t] = fmaxf(a[t] * rs + b1[c8 + t], 0.f);
        }
    }
    __syncthreads();

    // GEMM: 32 nodes x 32 cols; all 256 threads (node=tid/8, 4 cols each)
    const int n2 = tid >> 3;
    const int c4 = (tid & 7) * 4;
    float4 acc = make_float4(0.f, 0.f, 0.f, 0.f);
#pragma unroll 8
    for (int k = 0; k < 64; ++k) {
        const float xv = sh[n2][k];
        const float4 w = *(const float4*)(sW + k * 32 + c4);
        acc.x += xv * w.x; acc.y += xv * w.y; acc.z += xv * w.z; acc.w += xv * w.w;
    }
    const int gn = blockIdx.x * 32 + n2;
    if (gn < N) {
        const float s = rs_out[gn];
        uint2 pk;
        pk.x = f2bf(acc.x * s) | (f2bf(acc.y * s) << 16);
        pk.y = f2bf(acc.z * s) | (f2bf(acc.w * s) << 16);
        *(uint2*)(t2b + (size_t)gn * 32 + c4) = pk;
    }
}

// ---------------- C: gather(t2b,32) -> z (f32, d_out) + zb shadow ----------------
// 16 lanes/node = 4 col-lanes x 4 edge-quarters; combine via shfl_xor 4,8.
__global__ __launch_bounds__(256) void k_gather_C(
    const uint2* __restrict__ seg, const u16* __restrict__ csr,
    const u16* __restrict__ t2b, const float* __restrict__ rs_in,
    const float* __restrict__ rs_out, const float* __restrict__ b2,
    float* __restrict__ z, u16* __restrict__ zb, int N)
{
    const int node = blockIdx.x * 16 + (threadIdx.x >> 4);
    const int sub  = threadIdx.x & 15;
    const int qtr  = sub >> 2;
    const int c8   = (sub & 3) * 8;
    if (node >= N) return;               // 16-lane group exits together

    const uint2 sg = seg[node];
    const int j0 = (int)sg.x + qtr * (int)sg.y;
    const int j1 = j0 + (int)sg.y;

    float a[8];
#pragma unroll
    for (int t = 0; t < 8; ++t) a[t] = 0.f;
    for (int j = j0; j < j1; j += 4) GATHER4(t2b, 32);

#pragma unroll
    for (int t = 0; t < 8; ++t) {
        a[t] += __shfl_xor(a[t], 4);
        a[t] += __shfl_xor(a[t], 8);
    }
    if (qtr) return;

    const float rs = rs_in[node];
    float v[8];
#pragma unroll
    for (int t = 0; t < 8; ++t) v[t] = a[t] * rs + b2[c8 + t];

    float* o = z + (size_t)node * 32 + c8;
    *(float4*)(o)     = make_float4(v[0], v[1], v[2], v[3]);
    *(float4*)(o + 4) = make_float4(v[4], v[5], v[6], v[7]);

    const float ss = rs_out[node];
    uint4 pk;
    pk.x = f2bf(v[0] * ss) | (f2bf(v[1] * ss) << 16);
    pk.y = f2bf(v[2] * ss) | (f2bf(v[3] * ss) << 16);
    pk.z = f2bf(v[4] * ss) | (f2bf(v[5] * ss) << 16);
    pk.w = f2bf(v[6] * ss) | (f2bf(v[7] * ss) << 16);
    *(uint4*)(zb + (size_t)node * 32 + c8) = pk;
}

// ---------------- fused D: gather(zb,32) + @W3 + b3 -> recon ----------------
// 32 nodes/block: 2 gather batches (16 nodes x 16 lanes), then 256-thread GEMM.
__global__ __launch_bounds__(256) void k_gather_gemm_D(
    const uint2* __restrict__ seg, const u16* __restrict__ csr,
    const u16* __restrict__ zb, const float* __restrict__ rs_in,
    const float* __restrict__ W3, const float* __restrict__ b3,
    float* __restrict__ recon, int N)
{
    __shared__ float sa[32][36];
    __shared__ float sW[32 * 128];
    const int tid = threadIdx.x;

    for (int i = tid; i < 32 * 128 / 4; i += 256)
        ((float4*)sW)[i] = ((const float4*)W3)[i];

    const int nb   = tid >> 4;           // 16 node-groups in flight
    const int sub  = tid & 15;
    const int qtr  = sub >> 2;
    const int c8   = (sub & 3) * 8;

    uint2 sgs[2];                        // preload both batches' segments
#pragma unroll
    for (int b = 0; b < 2; ++b) {
        const int node = blockIdx.x * 32 + b * 16 + nb;
        sgs[b] = (node < N) ? seg[node] : make_uint2(0u, 0u);
    }

#pragma unroll
    for (int b = 0; b < 2; ++b) {
        const int nloc = b * 16 + nb;
        const int node = blockIdx.x * 32 + nloc;
        float a[8];
#pragma unroll
        for (int t = 0; t < 8; ++t) a[t] = 0.f;
        const int j0 = (int)sgs[b].x + qtr * (int)sgs[b].y;
        const int j1 = j0 + (int)sgs[b].y;
        for (int j = j0; j < j1; j += 4) GATHER4(zb, 32);
#pragma unroll
        for (int t = 0; t < 8; ++t) {
            a[t] += __shfl_xor(a[t], 4);
            a[t] += __shfl_xor(a[t], 8);
        }
        if (node < N && qtr == 0) {
            const float rs = rs_in[node];
#pragma unroll
            for (int t = 0; t < 8; ++t) sa[nloc][c8 + t] = a[t] * rs;
        }
    }
    __syncthreads();

    // GEMM: 32 nodes x 128 cols; thread -> 4 nodes x 4 cols
    const int ng = (tid >> 5) * 4;
    const int c4 = (tid & 31) * 4;
    const float4 bb = *(const float4*)(b3 + c4);
    float4 acc[4];
#pragma unroll
    for (int i = 0; i < 4; ++i) acc[i] = bb;
#pragma unroll 4
    for (int k = 0; k < 32; ++k) {
        const float4 w = *(const float4*)(sW + k * 128 + c4);
#pragma unroll
        for (int i = 0; i < 4; ++i) {
            const float xv = sa[ng + i][k];
            acc[i].x += xv * w.x; acc[i].y += xv * w.y;
            acc[i].z += xv * w.z; acc[i].w += xv * w.w;
        }
    }
#pragma unroll
    for (int i = 0; i < 4; ++i) {
        const int gn = blockIdx.x * 32 + ng + i;
        if (gn < N) *(float4*)(recon + (size_t)gn * 128 + c4) = acc[i];
    }
}

extern "C" void kernel_launch(void* const* d_in, const int* in_sizes, int n_in,
                              void* d_out, int out_size, void* d_ws, size_t ws_size,
                              hipStream_t stream) {
    const float* feat = (const float*)d_in[0];   // [N,128]
    const int*   src  = (const int*)d_in[1];     // [E]
    const int*   dst  = (const int*)d_in[2];     // [E]
    const float* W1   = (const float*)d_in[3];   // [128,64]
    const float* b1   = (const float*)d_in[4];   // [64]
    const float* W2   = (const float*)d_in[5];   // [64,32]
    const float* b2   = (const float*)d_in[6];   // [32]
    const float* W3   = (const float*)d_in[7];   // [32,128]
    const float* b3   = (const float*)d_in[8];   // [128]

    const int E = in_sizes[1];
    const int N = in_sizes[0] / 128;             // 50000 == NN
    const int slice_s = (((E + HPS - 1) / HPS) + 3) & ~3;
    const int slice_d = (((E + HPD - 1) / HPD) + 3) & ~3;
    const int CSRMAX = E + 15 * N;               // padded-csr upper bound (entries)
    const int ncw = CSRMAX / 2;                  // u32 words

    // ---- workspace layout (16B alignment at every boundary) ----
    const size_t SLABB = (size_t)(HPS + HPD) * NN;  // u8 slab = 8MB
    u8*  slab     = (u8*)d_ws;                    // dead after k_fill2
    uint2* seg    = (uint2*)(slab + SLABB);       // [N+16] (start, qlen)
    int* scan_p   = (int*)(seg + N + 16);         // [N]
    int* blocksum = scan_p + N;                   // [256]
    u16* csr      = (u16*)(blocksum + 256);       // [CSRMAX] u16 node ids
    float* rs_out = (float*)(csr + CSRMAX);       // [N]
    float* rs_in  = rs_out + N;                   // [N]
    u16* t2b      = (u16*)(rs_in + N);            // [(N+8),32] bf16 (+dummy row N)
    u16* zb       = t2b + (size_t)(N + 8) * 32;   // [(N+8),32] bf16 (z * rs_out)
    u8*  pad4     = (u8*)(zb + (size_t)(N + 8) * 32);  // [N] quarter lengths
    u16* t1b      = (u16*)slab;                   // [(N+1),64] bf16 = 6.4MB <= slab

    float* z_out  = (float*)d_out;                // [N,32]
    float* recon  = z_out + (size_t)N * 32;       // [N,128]

    const int B = 256;
    const int nb_scan = (N + 255) / 256;          // 196

    // ---- atomic-free graph preprocessing (padded CSR, u8 counts, u16 ids) ----
    k_hist1<<<HPS + HPD, B, 0, stream>>>(src, dst, slab, E, slice_s, slice_d);
    k_reduce_scan<<<nb_scan, B, 0, stream>>>(slab, rs_out, rs_in, scan_p, blocksum,
                                             pad4, (unsigned*)csr, ncw, N);
    k_scan23<<<nb_scan, B, 0, stream>>>(scan_p, blocksum, pad4, seg, N, nb_scan);
    k_fill2<<<FNB * HPD, B, 0, stream>>>(src, dst, seg, slab, csr, E, slice_d, N);

    // ---- A: t1b = bf16(rs_out .* (X @ W1)) via MFMA; zero dummy rows ----
    k_gemm_mfma_A<<<(N + 63) / 64, B, 0, stream>>>(
        feat, W1, rs_out, t1b, t2b, zb, N);

    // ---- B: gather(t1b) + relu + @W2 -> t2b ----
    k_gather_gemm_B<<<(N + 31) / 32, B, 0, stream>>>(
        seg, csr, t1b, rs_in, rs_out, b1, W2, t2b, N);

    // ---- C: gather(t2b) -> z (d_out) + zb shadow ----
    k_gather_C<<<(N + 15) / 16, B, 0, stream>>>(
        seg, csr, t2b, rs_in, rs_out, b2, z_out, zb, N);

    // ---- D: gather(zb) + @W3 + b3 -> recon ----
    k_gather_gemm_D<<<(N + 31) / 32, B, 0, stream>>>(
        seg, csr, zb, rs_in, W3, b3, recon, N);
}